// Round 2
// baseline (926.775 us; speedup 1.0000x reference)
//
#include <hip/hip_runtime.h>
#include <stdint.h>

typedef __bf16 bf16x8 __attribute__((ext_vector_type(8)));
typedef float  f32x4  __attribute__((ext_vector_type(4)));

#define F_TOT 8192
#define DIM   1024
#define NEXP  8
#define FF    4096
#define CAP   2560

__device__ __forceinline__ float b2f(unsigned short u){
    union { unsigned int u; float f; } c; c.u = ((unsigned int)u) << 16; return c.f;
}
__device__ __forceinline__ unsigned short f2b(float f){
    union { float f; unsigned int u; } c; c.f = f;
    unsigned int r = c.u + 0x7FFFu + ((c.u >> 16) & 1u);
    return (unsigned short)(r >> 16);
}
__device__ __forceinline__ float ldIn(const void* p, size_t i, int isb){
    return isb ? b2f(((const unsigned short*)p)[i]) : ((const float*)p)[i];
}
__device__ __forceinline__ void gl_lds16(const unsigned short* g, unsigned short* l){
    __builtin_amdgcn_global_load_lds(
        (const __attribute__((address_space(1))) unsigned int*)(g),
        (__attribute__((address_space(3))) unsigned int*)(l),
        16, 0, 0);
}

template<int W> __device__ __forceinline__ void waitcnt_vm(){
    if constexpr (W == 8)      asm volatile("s_waitcnt vmcnt(8)" ::: "memory");
    else if constexpr (W == 4) asm volatile("s_waitcnt vmcnt(4)" ::: "memory");
    else                       asm volatile("s_waitcnt vmcnt(0)" ::: "memory");
}

// ---------------- detect: bf16 vs fp32 inputs (write flag: 1=bf16) ----------
__global__ void detect_kernel(const unsigned short* __restrict__ x, int* __restrict__ flag){
    __shared__ int cnt;
    if (threadIdx.x == 0) cnt = 0;
    __syncthreads();
    unsigned short s = x[threadIdx.x];
    int e = s & 0x7F80;
    if (e >= 0x3000 && e <= 0x4800) atomicAdd(&cnt, 1);
    __syncthreads();
    if (threadIdx.x == 0) flag[0] = (cnt >= 410) ? 1 : 0;
}

// ---------------- gating ----------------------------------------------------
__global__ void gating_kernel(const void* __restrict__ x,
                              const void* __restrict__ Wg, const void* __restrict__ bg,
                              const void* __restrict__ Wn, const void* __restrict__ bn,
                              const int* __restrict__ flag,
                              float* __restrict__ logits, float* __restrict__ nlogits)
{
    int tid = blockIdx.x * blockDim.x + threadIdx.x;
    int t = tid >> 4, o = tid & 15;
    int col = o & 7;
    int isb = flag[0];
    const void* W = (o < 8) ? Wg : Wn;
    float acc = 0.f;
    if (isb){
        const unsigned short* xr = (const unsigned short*)x + (size_t)t * DIM;
        const unsigned short* w  = (const unsigned short*)W;
        #pragma unroll 8
        for (int d = 0; d < DIM; d++) acc = fmaf(b2f(xr[d]), b2f(w[d * 8 + col]), acc);
    } else {
        const float* xr = (const float*)x + (size_t)t * DIM;
        const float* w  = (const float*)W;
        #pragma unroll 8
        for (int d = 0; d < DIM; d++) acc = fmaf(xr[d], w[d * 8 + col], acc);
    }
    acc += ldIn((o < 8) ? bg : bn, col, isb);
    ((o < 8) ? logits : nlogits)[t * 8 + col] = acc;
}

// ---------------- route -----------------------------------------------------
__global__ void route_kernel(const float* __restrict__ logits,
                             const float* __restrict__ nlogits,
                             const void* __restrict__ noise,
                             const int* __restrict__ flag,
                             int* __restrict__ topi, float* __restrict__ gates)
{
    int t = blockIdx.x * blockDim.x + threadIdx.x;
    int isb = flag[0];
    float ny[8];
    #pragma unroll
    for (int e = 0; e < 8; e++){
        float nl = nlogits[t * 8 + e];
        float sp = fmaxf(nl, 0.f) + log1pf(expf(-fabsf(nl)));
        ny[e] = logits[t * 8 + e] + ldIn(noise, (size_t)t * 8 + e, isb) * sp;
    }
    int i0 = 0; float v0 = ny[0];
    #pragma unroll
    for (int e = 1; e < 8; e++) if (ny[e] > v0){ v0 = ny[e]; i0 = e; }
    int i1 = -1; float v1 = -3.4e38f;
    #pragma unroll
    for (int e = 0; e < 8; e++) if (e != i0 && ny[e] > v1){ v1 = ny[e]; i1 = e; }
    float e1 = expf(v1 - v0);
    float den = 1.f + e1;
    topi[t * 2]      = i0;  topi[t * 2 + 1] = i1;
    gates[t * 2]     = 1.f / den;
    gates[t * 2 + 1] = e1 / den;
}

// ---------------- scan: dispatch[e][pos]=t, slotf[t][k]=e*CAP+pos, cnt[e] ---
__global__ __launch_bounds__(1024)
void scan_kernel(const int* __restrict__ topi,
                 int* __restrict__ dispatch, int* __restrict__ slotf,
                 int* __restrict__ cntbuf)
{
    int e = blockIdx.x;
    int tid = threadIdx.x;
    for (int c = tid; c < CAP; c += 1024) dispatch[e * CAP + c] = F_TOT;
    int base = tid * 8;
    int kk[8]; int cnt = 0;
    #pragma unroll
    for (int j = 0; j < 8; j++){
        int t = base + j;
        int k = (topi[t * 2] == e) ? 0 : ((topi[t * 2 + 1] == e) ? 1 : -1);
        kk[j] = k; if (k >= 0) cnt++;
    }
    __shared__ int s[1024];
    s[tid] = cnt; __syncthreads();
    for (int off = 1; off < 1024; off <<= 1){
        int v = (tid >= off) ? s[tid - off] : 0;
        __syncthreads();
        s[tid] += v;
        __syncthreads();
    }
    if (tid == 1023) cntbuf[e] = s[1023];
    int pos = s[tid] - cnt;
    #pragma unroll
    for (int j = 0; j < 8; j++){
        if (kk[j] >= 0){
            int t = base + j;
            if (pos < CAP){
                dispatch[e * CAP + pos] = t;
                slotf[t * 2 + kk[j]] = e * CAP + pos;
            } else {
                slotf[t * 2 + kk[j]] = -1;     // dropped (over capacity)
            }
            pos++;
        }
    }
}

// ---------------- convert x -> bf16 -----------------------------------------
__global__ void convx_kernel(const void* __restrict__ x, const int* __restrict__ flag,
                             unsigned short* __restrict__ xb)
{
    size_t i = ((size_t)blockIdx.x * blockDim.x + threadIdx.x) * 8;
    if (flag[0]){
        ushort4 a = *(const ushort4*)((const unsigned short*)x + i);
        ushort4 b = *(const ushort4*)((const unsigned short*)x + i + 4);
        *(ushort4*)(xb + i) = a;  *(ushort4*)(xb + i + 4) = b;
    } else {
        float4 a = *(const float4*)((const float*)x + i);
        float4 b = *(const float4*)((const float*)x + i + 4);
        ushort4 lo, hi;
        lo.x = f2b(a.x); lo.y = f2b(a.y); lo.z = f2b(a.z); lo.w = f2b(a.w);
        hi.x = f2b(b.x); hi.y = f2b(b.y); hi.z = f2b(b.z); hi.w = f2b(b.w);
        *(ushort4*)(xb + i) = lo; *(ushort4*)(xb + i + 4) = hi;
    }
}

// ---------------- transpose (dual-dtype in, bf16 out) -----------------------
__global__ void transpose_kernel(const void* __restrict__ in,
                                 unsigned short* __restrict__ out,
                                 const int* __restrict__ flag,
                                 int R, int C, int eBase)
{
    __shared__ unsigned short tile[64][68];
    const size_t mi = (size_t)(eBase + blockIdx.z) * R * C;
    const size_t mo = (size_t)blockIdx.z * R * C;
    int c0 = blockIdx.x * 64, r0 = blockIdx.y * 64;
    int t = threadIdx.x;
    int rr = t >> 4, cc = (t & 15) * 4;
    int isb = flag[0];
    #pragma unroll
    for (int i = 0; i < 4; i++){
        int r = rr + i * 16;
        size_t idx = mi + (size_t)(r0 + r) * C + c0 + cc;
        if (isb){
            ushort4 v = *(const ushort4*)((const unsigned short*)in + idx);
            *(ushort4*)&tile[r][cc] = v;
        } else {
            float4 v = *(const float4*)((const float*)in + idx);
            ushort4 u; u.x = f2b(v.x); u.y = f2b(v.y); u.z = f2b(v.z); u.w = f2b(v.w);
            *(ushort4*)&tile[r][cc] = u;
        }
    }
    __syncthreads();
    #pragma unroll
    for (int i = 0; i < 4; i++){
        int c = rr + i * 16;
        ushort4 v;
        v.x = tile[cc + 0][c]; v.y = tile[cc + 1][c];
        v.z = tile[cc + 2][c]; v.w = tile[cc + 3][c];
        *(ushort4*)(out + mo + (size_t)(c0 + c) * R + r0 + cc) = v;
    }
}

// ---------------- pipelined FFN GEMM ----------------------------------------
// Ring of 4 BK=32 sub-tile slots; ONE raw s_barrier per sub-tile; counted
// vmcnt(8) (never 0 in steady state); reads issued before stage; setprio(1)
// around the MFMA cluster.  Swizzle: LDS dest linear, global source
// inverse-permuted (P = L ^ ((L>>2)&7)), read addr ^= ((row&7)<<4).
//
// Safety: barrier(s) guarantees (a) every wave's 4 stage-loads of sub-tile s
// completed (its own vmcnt(8) precedes the barrier), and (b) every wave
// finished READING sub-tile s-1 (compiler lgkmcnt precedes its MFMAs which
// precede the barrier).  So STAGE(s+3) into slot (s-1)&3 after the barrier is
// race-free; active window {s-1,s,s+1,s+2} = 4 distinct slots.

#define STAGE(k) { \
    unsigned short* sl_ = smem + (size_t)((k)&3)*(SLOT/2); \
    gl_lds16(aS0 + (size_t)(k)*32, sl_ + tid*8); \
    gl_lds16(aS1 + (size_t)(k)*32, sl_ + tid*8 + TH*8); \
    gl_lds16(bS0 + (size_t)(k)*32, sl_ + ABYTES/2 + tid*8); \
    gl_lds16(bS1 + (size_t)(k)*32, sl_ + ABYTES/2 + tid*8 + TH*8); }

#define BODY(S, DOSTAGE, VM) { \
    const int s_ = (S); \
    waitcnt_vm<VM>(); \
    __builtin_amdgcn_s_barrier(); \
    asm volatile("" ::: "memory"); \
    const char* base_ = (const char*)smem + (size_t)(s_&3)*SLOT; \
    bf16x8 afv[RM], bfv[RN]; \
    _Pragma("unroll") \
    for (int j = 0; j < RN; j++){ \
        int R_ = wn*(RN*16) + j*16 + l16; \
        bfv[j] = *(const bf16x8*)(base_ + ABYTES + (((R_<<6)|(quad<<4)) ^ sx)); \
    } \
    _Pragma("unroll") \
    for (int i = 0; i < RM; i++){ \
        int R_ = wm*(RM*16) + i*16 + l16; \
        afv[i] = *(const bf16x8*)(base_ + (((R_<<6)|(quad<<4)) ^ sx)); \
    } \
    if (DOSTAGE){ STAGE(s_+3); } \
    __builtin_amdgcn_s_setprio(1); \
    _Pragma("unroll") \
    for (int i = 0; i < RM; i++) \
        _Pragma("unroll") \
        for (int j = 0; j < RN; j++) \
            acc[i][j] = __builtin_amdgcn_mfma_f32_16x16x32_bf16(afv[i], bfv[j], acc[i][j], 0, 0, 0); \
    __builtin_amdgcn_s_setprio(0); \
}

template<int KT, int NT, int BM, int BN, int TH, int WM, int WN, bool ISF0>
__global__ __launch_bounds__(TH, 2)
void ffn_pipe_kernel(const unsigned short* __restrict__ Ain,   // xb or h
                     const unsigned short* __restrict__ Wt,    // [4][NT][KT] bf16
                     const void* __restrict__ bias,
                     const int* __restrict__ flag,
                     unsigned short* __restrict__ Out,         // h or eo
                     const int* __restrict__ dispatch,
                     const int* __restrict__ cnt,
                     int eBase)
{
    constexpr int NTN    = NT / BN;
    constexpr int NK     = KT / 32;
    constexpr int RM     = BM / WM / 16;
    constexpr int RN     = BN / WN / 16;
    constexpr int ABYTES = BM * 64;          // A bytes per slot
    constexpr int SLOT   = (BM + BN) * 64;   // bytes per ring slot

    __shared__ __align__(16) unsigned short smem[SLOT * 4 / 2];

    const int el = blockIdx.y, eg = el + eBase;
    const int nt = blockIdx.x % NTN;
    const int mt = blockIdx.x / NTN;
    const int m0 = mt * BM, n0 = nt * BN;
    if (m0 >= cnt[eg]) return;               // whole m-tile past expert row count

    const int tid = threadIdx.x, lane = tid & 63, wave = tid >> 6;
    const int wm = wave / WN, wn = wave % WN;
    const int quad = lane >> 4, l16 = lane & 15;
    const int sx = (l16 & 7) << 4;           // read-side XOR swizzle

    // invert P = L ^ ((L>>2)&7): logical unit for physical unit P
    const int P0 = tid, P1 = tid + TH;
    const int LA0 = (P0 & ~7) | ((((P0>>2)^(P0>>4))&1)<<2) | ((((P0>>1)^(P0>>3))&1)<<1) | ((P0^(P0>>2)^(P0>>4))&1);
    const int LA1 = (P1 & ~7) | ((((P1>>2)^(P1>>4))&1)<<2) | ((((P1>>1)^(P1>>3))&1)<<1) | ((P1^(P1>>2)^(P1>>4))&1);
    const int rA0 = LA0 >> 2, cA0 = (LA0 & 3) * 8;
    const int rA1 = LA1 >> 2, cA1 = (LA1 & 3) * 8;

    const unsigned short *aS0, *aS1;
    if (ISF0){
        int t0 = dispatch[eg * CAP + m0 + rA0];
        int t1 = dispatch[eg * CAP + m0 + rA1];
        if (((unsigned)t0) >= (unsigned)F_TOT) t0 = 0;
        if (((unsigned)t1) >= (unsigned)F_TOT) t1 = 0;
        aS0 = Ain + (size_t)t0 * KT + cA0;
        aS1 = Ain + (size_t)t1 * KT + cA1;
    } else {
        aS0 = Ain + ((size_t)(el * CAP + m0 + rA0)) * KT + cA0;
        aS1 = Ain + ((size_t)(el * CAP + m0 + rA1)) * KT + cA1;
    }
    const unsigned short* bE  = Wt + (size_t)el * NT * KT;
    const unsigned short* bS0 = bE + (size_t)(n0 + rA0) * KT + cA0;
    const unsigned short* bS1 = bE + (size_t)(n0 + rA1) * KT + cA1;

    f32x4 acc[RM][RN] = {};

    STAGE(0); STAGE(1); STAGE(2);

    for (int s = 0; s < NK - 3; ++s){ BODY(s, 1, 8); }
    BODY(NK - 3, 0, 8);
    BODY(NK - 2, 0, 4);
    BODY(NK - 1, 0, 0);

    // ---- epilogue: bias (+gelu for ffn0), bf16 store ----
    const int isb = flag[0];
    const int rBase = m0 + wm * (RM * 16) + quad * 4;
    const int cBase = n0 + wn * (RN * 16) + l16;
    float bv[RN];
    #pragma unroll
    for (int j = 0; j < RN; j++) bv[j] = ldIn(bias, (size_t)eg * NT + cBase + j * 16, isb);
    const int oe = ISF0 ? el : eg;
    #pragma unroll
    for (int i = 0; i < RM; i++)
        #pragma unroll
        for (int j = 0; j < RN; j++)
            #pragma unroll
            for (int r = 0; r < 4; r++){
                int row = rBase + i * 16 + r;
                float v = acc[i][j][r] + bv[j];
                if (ISF0) v = 0.5f * v * (1.0f + erff(v * 0.70710678118654752f));
                Out[((size_t)(oe * CAP + row)) * NT + cBase + j * 16] = f2b(v);
            }
}

// ---------------- combine: out[t] = g0*eo[s0] + g1*eo[s1] -------------------
__global__ void combine_kernel(const unsigned short* __restrict__ eo,
                               const int* __restrict__ slotf,
                               const float* __restrict__ gates,
                               const int* __restrict__ flag,
                               void* __restrict__ out)
{
    int t = blockIdx.x;
    int d = threadIdx.x * 4;
    int s0 = slotf[t * 2], s1 = slotf[t * 2 + 1];
    float g0 = gates[t * 2], g1 = gates[t * 2 + 1];
    float a0 = 0.f, a1 = 0.f, a2 = 0.f, a3 = 0.f;
    if (((unsigned)s0) < (unsigned)(NEXP * CAP)){
        ushort4 a = *(const ushort4*)(eo + (size_t)s0 * DIM + d);
        a0 += g0 * b2f(a.x); a1 += g0 * b2f(a.y);
        a2 += g0 * b2f(a.z); a3 += g0 * b2f(a.w);
    }
    if (((unsigned)s1) < (unsigned)(NEXP * CAP)){
        ushort4 a = *(const ushort4*)(eo + (size_t)s1 * DIM + d);
        a0 += g1 * b2f(a.x); a1 += g1 * b2f(a.y);
        a2 += g1 * b2f(a.z); a3 += g1 * b2f(a.w);
    }
    if (flag[0]){
        ushort4 o; o.x = f2b(a0); o.y = f2b(a1); o.z = f2b(a2); o.w = f2b(a3);
        *(ushort4*)((unsigned short*)out + (size_t)t * DIM + d) = o;
    } else {
        float4 o; o.x = a0; o.y = a1; o.z = a2; o.w = a3;
        *(float4*)((float*)out + (size_t)t * DIM + d) = o;
    }
}

// ---------------- launch ----------------------------------------------------
extern "C" void kernel_launch(void* const* d_in, const int* in_sizes, int n_in,
                              void* d_out, int out_size, void* d_ws, size_t ws_size,
                              hipStream_t stream)
{
    const void* x     = d_in[0];
    const void* noise = d_in[1];
    const void* Wg    = d_in[2];
    const void* bg    = d_in[3];
    const void* Wn    = d_in[4];
    const void* bn    = d_in[5];
    const void* W1    = d_in[6];
    const void* b1    = d_in[7];
    const void* W2    = d_in[8];
    const void* b2    = d_in[9];
    char* ws = (char*)d_ws;

    float* logits  = (float*)(ws + 0);            // 262144
    float* nlogits = (float*)(ws + 262144);       // 262144
    int*   topi    = (int*)  (ws + 524288);       // 65536
    float* gates   = (float*)(ws + 589824);       // 65536
    int*   disp    = (int*)  (ws + 655360);       // 81920
    int*   slotf   = (int*)  (ws + 737280);       // 65536
    int*   flag    = (int*)  (ws + 802816);       // 4
    int*   cnt     = (int*)  (ws + 803072);       // 32
    unsigned short* xb = (unsigned short*)(ws + 1048576);    // 16,777,216
    unsigned short* Wt = (unsigned short*)(ws + 17825792);   // 33,554,432 (4 experts)
    unsigned short* h  = (unsigned short*)(ws + 51380224);   // 83,886,080 (4 experts)
    unsigned short* eo = (unsigned short*)(ws + 135266304);  // 41,943,040 (8 experts)
    // total 177,209,344 B

    detect_kernel<<<1, 512, 0, stream>>>((const unsigned short*)x, flag);
    gating_kernel<<<512, 256, 0, stream>>>(x, Wg, bg, Wn, bn, flag, logits, nlogits);
    route_kernel<<<32, 256, 0, stream>>>(logits, nlogits, noise, flag, topi, gates);
    scan_kernel<<<8, 1024, 0, stream>>>(topi, disp, slotf, cnt);
    convx_kernel<<<4096, 256, 0, stream>>>(x, flag, xb);

    for (int g = 0; g < 2; g++){
        int eB = g * 4;
        transpose_kernel<<<dim3(64, 16, 4), 256, 0, stream>>>(W1, Wt, flag, DIM, FF, eB);
        // ffn0: 256x256 tile, 8 waves (2Mx4N), 1 block/CU, grid 16n x 10m x 4e
        ffn_pipe_kernel<DIM, FF, 256, 256, 512, 2, 4, true>
            <<<dim3((FF/256) * (CAP/256), 4), 512, 0, stream>>>(
            xb, Wt, b1, flag, h, disp, cnt, eB);
        transpose_kernel<<<dim3(16, 64, 4), 256, 0, stream>>>(W2, Wt, flag, FF, DIM, eB);
        // ffn1: 128x128 tile, 4 waves (2Mx2N), 2 blocks/CU, grid 8n x 20m x 4e
        ffn_pipe_kernel<FF, DIM, 128, 128, 256, 2, 2, false>
            <<<dim3((DIM/128) * (CAP/128), 4), 256, 0, stream>>>(
            h, Wt, b2, flag, eo, disp, cnt, eB);
    }
    combine_kernel<<<F_TOT, 256, 0, stream>>>(eo, slotf, gates, flag, d_out);
}

// Round 3
// 916.249 us; speedup vs baseline: 1.0115x; 1.0115x over previous
//
#include <hip/hip_runtime.h>
#include <stdint.h>

typedef __bf16 bf16x8 __attribute__((ext_vector_type(8)));
typedef float  f32x4  __attribute__((ext_vector_type(4)));

#define F_TOT 8192
#define DIM   1024
#define NEXP  8
#define FF    4096
#define CAP   2560

__device__ __forceinline__ float b2f(unsigned short u){
    union { unsigned int u; float f; } c; c.u = ((unsigned int)u) << 16; return c.f;
}
__device__ __forceinline__ unsigned short f2b(float f){
    union { float f; unsigned int u; } c; c.f = f;
    unsigned int r = c.u + 0x7FFFu + ((c.u >> 16) & 1u);
    return (unsigned short)(r >> 16);
}
__device__ __forceinline__ float ldIn(const void* p, size_t i, int isb){
    return isb ? b2f(((const unsigned short*)p)[i]) : ((const float*)p)[i];
}
__device__ __forceinline__ void gl_lds16(const unsigned short* g, unsigned short* l){
    __builtin_amdgcn_global_load_lds(
        (const __attribute__((address_space(1))) unsigned int*)(g),
        (__attribute__((address_space(3))) unsigned int*)(l),
        16, 0, 0);
}

template<int W> __device__ __forceinline__ void waitcnt_vm(){
    if constexpr (W == 8)      asm volatile("s_waitcnt vmcnt(8)" ::: "memory");
    else if constexpr (W == 4) asm volatile("s_waitcnt vmcnt(4)" ::: "memory");
    else                       asm volatile("s_waitcnt vmcnt(0)" ::: "memory");
}

// ---------------- detect: bf16 vs fp32 inputs (write flag: 1=bf16) ----------
__global__ void detect_kernel(const unsigned short* __restrict__ x, int* __restrict__ flag){
    __shared__ int cnt;
    if (threadIdx.x == 0) cnt = 0;
    __syncthreads();
    unsigned short s = x[threadIdx.x];
    int e = s & 0x7F80;
    if (e >= 0x3000 && e <= 0x4800) atomicAdd(&cnt, 1);
    __syncthreads();
    if (threadIdx.x == 0) flag[0] = (cnt >= 410) ? 1 : 0;
}

// ---------------- gating ----------------------------------------------------
__global__ void gating_kernel(const void* __restrict__ x,
                              const void* __restrict__ Wg, const void* __restrict__ bg,
                              const void* __restrict__ Wn, const void* __restrict__ bn,
                              const int* __restrict__ flag,
                              float* __restrict__ logits, float* __restrict__ nlogits)
{
    int tid = blockIdx.x * blockDim.x + threadIdx.x;
    int t = tid >> 4, o = tid & 15;
    int col = o & 7;
    int isb = flag[0];
    const void* W = (o < 8) ? Wg : Wn;
    float acc = 0.f;
    if (isb){
        const unsigned short* xr = (const unsigned short*)x + (size_t)t * DIM;
        const unsigned short* w  = (const unsigned short*)W;
        #pragma unroll 8
        for (int d = 0; d < DIM; d++) acc = fmaf(b2f(xr[d]), b2f(w[d * 8 + col]), acc);
    } else {
        const float* xr = (const float*)x + (size_t)t * DIM;
        const float* w  = (const float*)W;
        #pragma unroll 8
        for (int d = 0; d < DIM; d++) acc = fmaf(xr[d], w[d * 8 + col], acc);
    }
    acc += ldIn((o < 8) ? bg : bn, col, isb);
    ((o < 8) ? logits : nlogits)[t * 8 + col] = acc;
}

// ---------------- route -----------------------------------------------------
__global__ void route_kernel(const float* __restrict__ logits,
                             const float* __restrict__ nlogits,
                             const void* __restrict__ noise,
                             const int* __restrict__ flag,
                             int* __restrict__ topi, float* __restrict__ gates)
{
    int t = blockIdx.x * blockDim.x + threadIdx.x;
    int isb = flag[0];
    float ny[8];
    #pragma unroll
    for (int e = 0; e < 8; e++){
        float nl = nlogits[t * 8 + e];
        float sp = fmaxf(nl, 0.f) + log1pf(expf(-fabsf(nl)));
        ny[e] = logits[t * 8 + e] + ldIn(noise, (size_t)t * 8 + e, isb) * sp;
    }
    int i0 = 0; float v0 = ny[0];
    #pragma unroll
    for (int e = 1; e < 8; e++) if (ny[e] > v0){ v0 = ny[e]; i0 = e; }
    int i1 = -1; float v1 = -3.4e38f;
    #pragma unroll
    for (int e = 0; e < 8; e++) if (e != i0 && ny[e] > v1){ v1 = ny[e]; i1 = e; }
    float e1 = expf(v1 - v0);
    float den = 1.f + e1;
    topi[t * 2]      = i0;  topi[t * 2 + 1] = i1;
    gates[t * 2]     = 1.f / den;
    gates[t * 2 + 1] = e1 / den;
}

// ---------------- scan: dispatch[e][pos]=t, slotf[t][k]=e*CAP+pos, cnt[e] ---
__global__ __launch_bounds__(1024)
void scan_kernel(const int* __restrict__ topi,
                 int* __restrict__ dispatch, int* __restrict__ slotf,
                 int* __restrict__ cntbuf)
{
    int e = blockIdx.x;
    int tid = threadIdx.x;
    for (int c = tid; c < CAP; c += 1024) dispatch[e * CAP + c] = F_TOT;
    int base = tid * 8;
    int kk[8]; int cnt = 0;
    #pragma unroll
    for (int j = 0; j < 8; j++){
        int t = base + j;
        int k = (topi[t * 2] == e) ? 0 : ((topi[t * 2 + 1] == e) ? 1 : -1);
        kk[j] = k; if (k >= 0) cnt++;
    }
    __shared__ int s[1024];
    s[tid] = cnt; __syncthreads();
    for (int off = 1; off < 1024; off <<= 1){
        int v = (tid >= off) ? s[tid - off] : 0;
        __syncthreads();
        s[tid] += v;
        __syncthreads();
    }
    if (tid == 1023) cntbuf[e] = s[1023];
    int pos = s[tid] - cnt;
    #pragma unroll
    for (int j = 0; j < 8; j++){
        if (kk[j] >= 0){
            int t = base + j;
            if (pos < CAP){
                dispatch[e * CAP + pos] = t;
                slotf[t * 2 + kk[j]] = e * CAP + pos;
            } else {
                slotf[t * 2 + kk[j]] = -1;     // dropped (over capacity)
            }
            pos++;
        }
    }
}

// ---------------- convert x -> bf16 -----------------------------------------
__global__ void convx_kernel(const void* __restrict__ x, const int* __restrict__ flag,
                             unsigned short* __restrict__ xb)
{
    size_t i = ((size_t)blockIdx.x * blockDim.x + threadIdx.x) * 8;
    if (flag[0]){
        ushort4 a = *(const ushort4*)((const unsigned short*)x + i);
        ushort4 b = *(const ushort4*)((const unsigned short*)x + i + 4);
        *(ushort4*)(xb + i) = a;  *(ushort4*)(xb + i + 4) = b;
    } else {
        float4 a = *(const float4*)((const float*)x + i);
        float4 b = *(const float4*)((const float*)x + i + 4);
        ushort4 lo, hi;
        lo.x = f2b(a.x); lo.y = f2b(a.y); lo.z = f2b(a.z); lo.w = f2b(a.w);
        hi.x = f2b(b.x); hi.y = f2b(b.y); hi.z = f2b(b.z); hi.w = f2b(b.w);
        *(ushort4*)(xb + i) = lo; *(ushort4*)(xb + i + 4) = hi;
    }
}

// ---------------- transpose (dual-dtype in, bf16 out) -----------------------
__global__ void transpose_kernel(const void* __restrict__ in,
                                 unsigned short* __restrict__ out,
                                 const int* __restrict__ flag,
                                 int R, int C, int eBase)
{
    __shared__ unsigned short tile[64][68];
    const size_t mi = (size_t)(eBase + blockIdx.z) * R * C;
    const size_t mo = (size_t)blockIdx.z * R * C;
    int c0 = blockIdx.x * 64, r0 = blockIdx.y * 64;
    int t = threadIdx.x;
    int rr = t >> 4, cc = (t & 15) * 4;
    int isb = flag[0];
    #pragma unroll
    for (int i = 0; i < 4; i++){
        int r = rr + i * 16;
        size_t idx = mi + (size_t)(r0 + r) * C + c0 + cc;
        if (isb){
            ushort4 v = *(const ushort4*)((const unsigned short*)in + idx);
            *(ushort4*)&tile[r][cc] = v;
        } else {
            float4 v = *(const float4*)((const float*)in + idx);
            ushort4 u; u.x = f2b(v.x); u.y = f2b(v.y); u.z = f2b(v.z); u.w = f2b(v.w);
            *(ushort4*)&tile[r][cc] = u;
        }
    }
    __syncthreads();
    #pragma unroll
    for (int i = 0; i < 4; i++){
        int c = rr + i * 16;
        ushort4 v;
        v.x = tile[cc + 0][c]; v.y = tile[cc + 1][c];
        v.z = tile[cc + 2][c]; v.w = tile[cc + 3][c];
        *(ushort4*)(out + mo + (size_t)(c0 + c) * R + r0 + cc) = v;
    }
}

// ---------------- pipelined FFN GEMM (decoupled frag reads) ------------------
// Ring of 4 BK=32 slots, ONE raw s_barrier per sub-tile, counted vmcnt.
// NEW vs prev round: A-fragments are DOUBLE-BUFFERED in registers.  At iter s
// (after barrier certifying slot s+1 via vmcnt(4)):
//   read bfv(s)   [4 ds_reads, in-phase; slot s certified at barrier s-1]
//   read afNXT(s+1) [8 ds_reads, consumed NEXT iter -> drain under MFMA(s)]
//   STAGE(s+3)
//   MFMA(s) from afCUR (loaded last iter) x bfv -> lgkm waits only bfv's 4.
// Hazards (ring 4): STAGE(s+3) targets slot (s-1)&3; all reads of slot s-1
// completed before MFMA(s-1) (lgkm) which precedes barrier(s).  Reads of
// slot s+1 precede writes STAGE(s+5) (issued iter s+2, after barrier s+2,
// by which time MFMA(s+1) consumed them).  Race-free.

#define STAGE(k) { \
    unsigned short* sl_ = smem + (size_t)((k)&3)*(SLOT/2); \
    gl_lds16(aS0 + (size_t)(k)*32, sl_ + tid*8); \
    gl_lds16(aS1 + (size_t)(k)*32, sl_ + tid*8 + TH*8); \
    gl_lds16(bS0 + (size_t)(k)*32, sl_ + ABYTES/2 + tid*8); \
    gl_lds16(bS1 + (size_t)(k)*32, sl_ + ABYTES/2 + tid*8 + TH*8); }

#define READ_A(AF_, S_) { \
    const char* ab_ = (const char*)smem + (size_t)((S_)&3)*SLOT; \
    _Pragma("unroll") \
    for (int i = 0; i < RM; i++){ \
        int R_ = wm*(RM*16) + i*16 + l16; \
        AF_[i] = *(const bf16x8*)(ab_ + (((R_<<6)|(quad<<4)) ^ sx)); } }

#define READ_B(BF_, S_) { \
    const char* bb_ = (const char*)smem + (size_t)((S_)&3)*SLOT + ABYTES; \
    _Pragma("unroll") \
    for (int j = 0; j < RN; j++){ \
        int R_ = wn*(RN*16) + j*16 + l16; \
        BF_[j] = *(const bf16x8*)(bb_ + (((R_<<6)|(quad<<4)) ^ sx)); } }

#define MFMAS(AF_, BF_) { \
    __builtin_amdgcn_s_setprio(1); \
    _Pragma("unroll") \
    for (int i = 0; i < RM; i++) \
        _Pragma("unroll") \
        for (int j = 0; j < RN; j++) \
            acc[i][j] = __builtin_amdgcn_mfma_f32_16x16x32_bf16(AF_[i], BF_[j], acc[i][j], 0, 0, 0); \
    __builtin_amdgcn_s_setprio(0); }

#define ITER(S_, CUR_, NXT_, VM_, DORD_, DOST_) { \
    waitcnt_vm<VM_>(); \
    __builtin_amdgcn_s_barrier(); \
    asm volatile("" ::: "memory"); \
    READ_B(bfv, (S_)); \
    if (DORD_){ READ_A(NXT_, (S_)+1); } \
    if (DOST_){ STAGE((S_)+3); } \
    MFMAS(CUR_, bfv); }

template<int KT, int NT, int BM, int BN, int TH, int WM, int WN, bool ISF0>
__global__ __launch_bounds__(TH, 2)
void ffn_pipe_kernel(const unsigned short* __restrict__ Ain,   // xb or h
                     const unsigned short* __restrict__ Wt,    // [4][NT][KT] bf16
                     const void* __restrict__ bias,
                     const int* __restrict__ flag,
                     unsigned short* __restrict__ Out,         // h or eo
                     const int* __restrict__ dispatch,
                     const int* __restrict__ cnt,
                     int eBase)
{
    constexpr int NTN    = NT / BN;
    constexpr int NK     = KT / 32;
    constexpr int RM     = BM / WM / 16;
    constexpr int RN     = BN / WN / 16;
    constexpr int ABYTES = BM * 64;          // A bytes per slot
    constexpr int SLOT   = (BM + BN) * 64;   // bytes per ring slot

    __shared__ __align__(16) unsigned short smem[SLOT * 4 / 2];

    const int el = blockIdx.y, eg = el + eBase;
    const int nt = blockIdx.x % NTN;
    const int mt = blockIdx.x / NTN;
    const int m0 = mt * BM, n0 = nt * BN;
    if (m0 >= cnt[eg]) return;               // whole m-tile past expert row count

    const int tid = threadIdx.x, lane = tid & 63, wave = tid >> 6;
    const int wm = wave / WN, wn = wave % WN;
    const int quad = lane >> 4, l16 = lane & 15;
    const int sx = (l16 & 7) << 4;           // read-side XOR swizzle

    // invert P = L ^ ((L>>2)&7): logical unit for physical unit P
    const int P0 = tid, P1 = tid + TH;
    const int LA0 = (P0 & ~7) | ((((P0>>2)^(P0>>4))&1)<<2) | ((((P0>>1)^(P0>>3))&1)<<1) | ((P0^(P0>>2)^(P0>>4))&1);
    const int LA1 = (P1 & ~7) | ((((P1>>2)^(P1>>4))&1)<<2) | ((((P1>>1)^(P1>>3))&1)<<1) | ((P1^(P1>>2)^(P1>>4))&1);
    const int rA0 = LA0 >> 2, cA0 = (LA0 & 3) * 8;
    const int rA1 = LA1 >> 2, cA1 = (LA1 & 3) * 8;

    const unsigned short *aS0, *aS1;
    if (ISF0){
        int t0 = dispatch[eg * CAP + m0 + rA0];
        int t1 = dispatch[eg * CAP + m0 + rA1];
        if (((unsigned)t0) >= (unsigned)F_TOT) t0 = 0;
        if (((unsigned)t1) >= (unsigned)F_TOT) t1 = 0;
        aS0 = Ain + (size_t)t0 * KT + cA0;
        aS1 = Ain + (size_t)t1 * KT + cA1;
    } else {
        aS0 = Ain + ((size_t)(el * CAP + m0 + rA0)) * KT + cA0;
        aS1 = Ain + ((size_t)(el * CAP + m0 + rA1)) * KT + cA1;
    }
    const unsigned short* bE  = Wt + (size_t)el * NT * KT;
    const unsigned short* bS0 = bE + (size_t)(n0 + rA0) * KT + cA0;
    const unsigned short* bS1 = bE + (size_t)(n0 + rA1) * KT + cA1;

    f32x4 acc[RM][RN] = {};
    bf16x8 afA[RM], afB[RM], bfv[RN];

    // prologue
    STAGE(0); STAGE(1); STAGE(2);
    waitcnt_vm<8>();
    __builtin_amdgcn_s_barrier();
    asm volatile("" ::: "memory");
    READ_A(afA, 0);

    for (int s = 0; s < NK - 4; s += 2){
        ITER(s,     afA, afB, 4, 1, 1);
        ITER(s + 1, afB, afA, 4, 1, 1);
    }
    ITER(NK - 4, afA, afB, 4, 1, 1);   // stages NK-1 (last stage)
    ITER(NK - 3, afB, afA, 4, 1, 0);
    ITER(NK - 2, afA, afB, 0, 1, 0);
    ITER(NK - 1, afB, afA, 0, 0, 0);

    // ---- epilogue: bias (+gelu for ffn0), bf16 store ----
    const int isb = flag[0];
    const int rBase = m0 + wm * (RM * 16) + quad * 4;
    const int cBase = n0 + wn * (RN * 16) + l16;
    float bv[RN];
    #pragma unroll
    for (int j = 0; j < RN; j++) bv[j] = ldIn(bias, (size_t)eg * NT + cBase + j * 16, isb);
    const int oe = ISF0 ? el : eg;
    #pragma unroll
    for (int i = 0; i < RM; i++)
        #pragma unroll
        for (int j = 0; j < RN; j++)
            #pragma unroll
            for (int r = 0; r < 4; r++){
                int row = rBase + i * 16 + r;
                float v = acc[i][j][r] + bv[j];
                if (ISF0) v = 0.5f * v * (1.0f + erff(v * 0.70710678118654752f));
                Out[((size_t)(oe * CAP + row)) * NT + cBase + j * 16] = f2b(v);
            }
}

// ---------------- combine: out[t] = g0*eo[s0] + g1*eo[s1] -------------------
__global__ void combine_kernel(const unsigned short* __restrict__ eo,
                               const int* __restrict__ slotf,
                               const float* __restrict__ gates,
                               const int* __restrict__ flag,
                               void* __restrict__ out)
{
    int t = blockIdx.x;
    int d = threadIdx.x * 4;
    int s0 = slotf[t * 2], s1 = slotf[t * 2 + 1];
    float g0 = gates[t * 2], g1 = gates[t * 2 + 1];
    float a0 = 0.f, a1 = 0.f, a2 = 0.f, a3 = 0.f;
    if (((unsigned)s0) < (unsigned)(NEXP * CAP)){
        ushort4 a = *(const ushort4*)(eo + (size_t)s0 * DIM + d);
        a0 += g0 * b2f(a.x); a1 += g0 * b2f(a.y);
        a2 += g0 * b2f(a.z); a3 += g0 * b2f(a.w);
    }
    if (((unsigned)s1) < (unsigned)(NEXP * CAP)){
        ushort4 a = *(const ushort4*)(eo + (size_t)s1 * DIM + d);
        a0 += g1 * b2f(a.x); a1 += g1 * b2f(a.y);
        a2 += g1 * b2f(a.z); a3 += g1 * b2f(a.w);
    }
    if (flag[0]){
        ushort4 o; o.x = f2b(a0); o.y = f2b(a1); o.z = f2b(a2); o.w = f2b(a3);
        *(ushort4*)((unsigned short*)out + (size_t)t * DIM + d) = o;
    } else {
        float4 o; o.x = a0; o.y = a1; o.z = a2; o.w = a3;
        *(float4*)((float*)out + (size_t)t * DIM + d) = o;
    }
}

// ---------------- launch ----------------------------------------------------
extern "C" void kernel_launch(void* const* d_in, const int* in_sizes, int n_in,
                              void* d_out, int out_size, void* d_ws, size_t ws_size,
                              hipStream_t stream)
{
    const void* x     = d_in[0];
    const void* noise = d_in[1];
    const void* Wg    = d_in[2];
    const void* bg    = d_in[3];
    const void* Wn    = d_in[4];
    const void* bn    = d_in[5];
    const void* W1    = d_in[6];
    const void* b1    = d_in[7];
    const void* W2    = d_in[8];
    const void* b2    = d_in[9];
    char* ws = (char*)d_ws;

    float* logits  = (float*)(ws + 0);            // 262144
    float* nlogits = (float*)(ws + 262144);       // 262144
    int*   topi    = (int*)  (ws + 524288);       // 65536
    float* gates   = (float*)(ws + 589824);       // 65536
    int*   disp    = (int*)  (ws + 655360);       // 81920
    int*   slotf   = (int*)  (ws + 737280);       // 65536
    int*   flag    = (int*)  (ws + 802816);       // 4
    int*   cnt     = (int*)  (ws + 803072);       // 32
    unsigned short* xb = (unsigned short*)(ws + 1048576);    // 16,777,216
    unsigned short* Wt = (unsigned short*)(ws + 17825792);   // 33,554,432 (4 experts)
    unsigned short* h  = (unsigned short*)(ws + 51380224);   // 83,886,080 (4 experts)
    unsigned short* eo = (unsigned short*)(ws + 135266304);  // 41,943,040 (8 experts)
    // total 177,209,344 B

    detect_kernel<<<1, 512, 0, stream>>>((const unsigned short*)x, flag);
    gating_kernel<<<512, 256, 0, stream>>>(x, Wg, bg, Wn, bn, flag, logits, nlogits);
    route_kernel<<<32, 256, 0, stream>>>(logits, nlogits, noise, flag, topi, gates);
    scan_kernel<<<8, 1024, 0, stream>>>(topi, disp, slotf, cnt);
    convx_kernel<<<4096, 256, 0, stream>>>(x, flag, xb);

    for (int g = 0; g < 2; g++){
        int eB = g * 4;
        transpose_kernel<<<dim3(64, 16, 4), 256, 0, stream>>>(W1, Wt, flag, DIM, FF, eB);
        // ffn0: 256x256 tile, 8 waves (2Mx4N), 1 block/CU
        ffn_pipe_kernel<DIM, FF, 256, 256, 512, 2, 4, true>
            <<<dim3((FF/256) * (CAP/256), 4), 512, 0, stream>>>(
            xb, Wt, b1, flag, h, disp, cnt, eB);
        transpose_kernel<<<dim3(16, 64, 4), 256, 0, stream>>>(W2, Wt, flag, FF, DIM, eB);
        // ffn1: 128x128 tile, 4 waves (2Mx2N), 2 blocks/CU
        ffn_pipe_kernel<FF, DIM, 128, 128, 256, 2, 2, false>
            <<<dim3((DIM/128) * (CAP/128), 4), 256, 0, stream>>>(
            h, Wt, b2, flag, eo, disp, cnt, eB);
    }
    combine_kernel<<<F_TOT, 256, 0, stream>>>(eo, slotf, gates, flag, d_out);
}

// Round 4
// 853.811 us; speedup vs baseline: 1.0855x; 1.0731x over previous
//
#include <hip/hip_runtime.h>
#include <stdint.h>

typedef __bf16 bf16x8 __attribute__((ext_vector_type(8)));
typedef float  f32x4  __attribute__((ext_vector_type(4)));

#define F_TOT 8192
#define DIM   1024
#define NEXP  8
#define FF    4096
#define CAP   2560

__device__ __forceinline__ float b2f(unsigned short u){
    union { unsigned int u; float f; } c; c.u = ((unsigned int)u) << 16; return c.f;
}
__device__ __forceinline__ unsigned short f2b(float f){
    union { float f; unsigned int u; } c; c.f = f;
    unsigned int r = c.u + 0x7FFFu + ((c.u >> 16) & 1u);
    return (unsigned short)(r >> 16);
}
__device__ __forceinline__ float ldIn(const void* p, size_t i, int isb){
    return isb ? b2f(((const unsigned short*)p)[i]) : ((const float*)p)[i];
}
__device__ __forceinline__ void gl_lds16(const unsigned short* g, unsigned short* l){
    __builtin_amdgcn_global_load_lds(
        (const __attribute__((address_space(1))) unsigned int*)(g),
        (__attribute__((address_space(3))) unsigned int*)(l),
        16, 0, 0);
}

// ---------------- fused: detect + gating + route + convx --------------------
// 512 blocks x 256 threads; block g owns tokens [16g, 16g+16).
__global__ __launch_bounds__(256)
void gating_kernel(const void* __restrict__ x,
                   const void* __restrict__ noise,
                   const void* __restrict__ Wg, const void* __restrict__ bg,
                   const void* __restrict__ Wn, const void* __restrict__ bn,
                   int* __restrict__ flag,
                   int* __restrict__ topi, float* __restrict__ gates,
                   unsigned short* __restrict__ xb)
{
    __shared__ int sflag;
    __shared__ float lg[16][17];     // [token][0..7 logits | 8..15 noise-logits]
    const int g = blockIdx.x, tid = threadIdx.x;
    const unsigned short* xs = (const unsigned short*)x;

    // ---- detect (replicates original 512-sample test per block) ----
    if (tid == 0) sflag = 0;
    __syncthreads();
    {
        int c = 0;
        unsigned short s0 = xs[tid], s1 = xs[tid + 256];
        int e0 = s0 & 0x7F80, e1 = s1 & 0x7F80;
        if (e0 >= 0x3000 && e0 <= 0x4800) c++;
        if (e1 >= 0x3000 && e1 <= 0x4800) c++;
        if (c) atomicAdd(&sflag, c);
    }
    __syncthreads();
    const int isb = (sflag >= 410) ? 1 : 0;
    if (g == 0 && tid == 0) flag[0] = isb;

    // ---- gating dot: 16 tokens x 16 outputs (8 logit + 8 noise-logit) ----
    const int tl = tid >> 4, o = tid & 15, col = o & 7;
    const int t = g * 16 + tl;
    const void* W = (o < 8) ? Wg : Wn;
    float acc = 0.f;
    if (isb){
        const unsigned short* xr = xs + (size_t)t * DIM;
        const unsigned short* w  = (const unsigned short*)W;
        for (int d = 0; d < DIM; d += 8){
            ushort4 a = *(const ushort4*)(xr + d);
            ushort4 b = *(const ushort4*)(xr + d + 4);
            acc = fmaf(b2f(a.x), b2f(w[(d+0)*8+col]), acc);
            acc = fmaf(b2f(a.y), b2f(w[(d+1)*8+col]), acc);
            acc = fmaf(b2f(a.z), b2f(w[(d+2)*8+col]), acc);
            acc = fmaf(b2f(a.w), b2f(w[(d+3)*8+col]), acc);
            acc = fmaf(b2f(b.x), b2f(w[(d+4)*8+col]), acc);
            acc = fmaf(b2f(b.y), b2f(w[(d+5)*8+col]), acc);
            acc = fmaf(b2f(b.z), b2f(w[(d+6)*8+col]), acc);
            acc = fmaf(b2f(b.w), b2f(w[(d+7)*8+col]), acc);
        }
    } else {
        const float* xr = (const float*)x + (size_t)t * DIM;
        const float* w  = (const float*)W;
        for (int d = 0; d < DIM; d += 8){
            float4 a = *(const float4*)(xr + d);
            float4 b = *(const float4*)(xr + d + 4);
            acc = fmaf(a.x, w[(d+0)*8+col], acc);
            acc = fmaf(a.y, w[(d+1)*8+col], acc);
            acc = fmaf(a.z, w[(d+2)*8+col], acc);
            acc = fmaf(a.w, w[(d+3)*8+col], acc);
            acc = fmaf(b.x, w[(d+4)*8+col], acc);
            acc = fmaf(b.y, w[(d+5)*8+col], acc);
            acc = fmaf(b.z, w[(d+6)*8+col], acc);
            acc = fmaf(b.w, w[(d+7)*8+col], acc);
        }
    }
    acc += ldIn((o < 8) ? bg : bn, col, isb);
    lg[tl][o] = acc;
    __syncthreads();

    // ---- route (one thread per token) ----
    if (tid < 16){
        const int tt = g * 16 + tid;
        float ny[8];
        #pragma unroll
        for (int e = 0; e < 8; e++){
            float nl = lg[tid][8 + e];
            float sp = fmaxf(nl, 0.f) + log1pf(expf(-fabsf(nl)));
            ny[e] = lg[tid][e] + ldIn(noise, (size_t)tt * 8 + e, isb) * sp;
        }
        int i0 = 0; float v0 = ny[0];
        #pragma unroll
        for (int e = 1; e < 8; e++) if (ny[e] > v0){ v0 = ny[e]; i0 = e; }
        int i1 = -1; float v1 = -3.4e38f;
        #pragma unroll
        for (int e = 0; e < 8; e++) if (e != i0 && ny[e] > v1){ v1 = ny[e]; i1 = e; }
        float e1 = expf(v1 - v0);
        float den = 1.f + e1;
        topi[tt * 2]      = i0;  topi[tt * 2 + 1] = i1;
        gates[tt * 2]     = 1.f / den;
        gates[tt * 2 + 1] = e1 / den;
    }

    // ---- convx: convert this block's 16 rows (16384 elements) to bf16 ----
    const size_t base = (size_t)g * 16384;
    #pragma unroll
    for (int it = 0; it < 8; it++){
        size_t i = base + (size_t)it * 2048 + tid * 8;
        if (isb){
            ushort4 a = *(const ushort4*)(xs + i);
            ushort4 b = *(const ushort4*)(xs + i + 4);
            *(ushort4*)(xb + i) = a;  *(ushort4*)(xb + i + 4) = b;
        } else {
            float4 a = *(const float4*)((const float*)x + i);
            float4 b = *(const float4*)((const float*)x + i + 4);
            ushort4 lo, hi;
            lo.x = f2b(a.x); lo.y = f2b(a.y); lo.z = f2b(a.z); lo.w = f2b(a.w);
            hi.x = f2b(b.x); hi.y = f2b(b.y); hi.z = f2b(b.z); hi.w = f2b(b.w);
            *(ushort4*)(xb + i) = lo; *(ushort4*)(xb + i + 4) = hi;
        }
    }
}

// ---------------- scan: dispatch[e][pos]=t, slotf[t][k]=e*CAP+pos, cnt[e] ---
__global__ __launch_bounds__(1024)
void scan_kernel(const int* __restrict__ topi,
                 int* __restrict__ dispatch, int* __restrict__ slotf,
                 int* __restrict__ cntbuf)
{
    int e = blockIdx.x;
    int tid = threadIdx.x;
    for (int c = tid; c < CAP; c += 1024) dispatch[e * CAP + c] = F_TOT;
    int base = tid * 8;
    int kk[8]; int cnt = 0;
    #pragma unroll
    for (int j = 0; j < 8; j++){
        int t = base + j;
        int k = (topi[t * 2] == e) ? 0 : ((topi[t * 2 + 1] == e) ? 1 : -1);
        kk[j] = k; if (k >= 0) cnt++;
    }
    __shared__ int s[1024];
    s[tid] = cnt; __syncthreads();
    for (int off = 1; off < 1024; off <<= 1){
        int v = (tid >= off) ? s[tid - off] : 0;
        __syncthreads();
        s[tid] += v;
        __syncthreads();
    }
    if (tid == 1023){ int tot = s[1023]; cntbuf[e] = tot > CAP ? CAP : tot; }
    int pos = s[tid] - cnt;
    #pragma unroll
    for (int j = 0; j < 8; j++){
        if (kk[j] >= 0){
            int t = base + j;
            if (pos < CAP){
                dispatch[e * CAP + pos] = t;
                slotf[t * 2 + kk[j]] = e * CAP + pos;
            } else {
                slotf[t * 2 + kk[j]] = -1;     // dropped (over capacity)
            }
            pos++;
        }
    }
}

// ---------------- transpose (dual-dtype in, bf16 out) -----------------------
__global__ void transpose_kernel(const void* __restrict__ in,
                                 unsigned short* __restrict__ out,
                                 const int* __restrict__ flag,
                                 int R, int C, int eBase)
{
    __shared__ unsigned short tile[64][68];
    const size_t mi = (size_t)(eBase + blockIdx.z) * R * C;
    const size_t mo = (size_t)blockIdx.z * R * C;
    int c0 = blockIdx.x * 64, r0 = blockIdx.y * 64;
    int t = threadIdx.x;
    int rr = t >> 4, cc = (t & 15) * 4;
    int isb = flag[0];
    #pragma unroll
    for (int i = 0; i < 4; i++){
        int r = rr + i * 16;
        size_t idx = mi + (size_t)(r0 + r) * C + c0 + cc;
        if (isb){
            ushort4 v = *(const ushort4*)((const unsigned short*)in + idx);
            *(ushort4*)&tile[r][cc] = v;
        } else {
            float4 v = *(const float4*)((const float*)in + idx);
            ushort4 u; u.x = f2b(v.x); u.y = f2b(v.y); u.z = f2b(v.z); u.w = f2b(v.w);
            *(ushort4*)&tile[r][cc] = u;
        }
    }
    __syncthreads();
    #pragma unroll
    for (int i = 0; i < 4; i++){
        int c = rr + i * 16;
        ushort4 v;
        v.x = tile[cc + 0][c]; v.y = tile[cc + 1][c];
        v.z = tile[cc + 2][c]; v.w = tile[cc + 3][c];
        *(ushort4*)(out + mo + (size_t)(c0 + c) * R + r0 + cc) = v;
    }
}

// ---------------- ffn0: h = gelu(gather(x)@W1t^T + b1) ----------------------
// grid: x = 32*20 (nt fastest), y = 4 experts
__global__ __launch_bounds__(256, 2)
void ffn0_kernel(const unsigned short* __restrict__ xb,
                 const unsigned short* __restrict__ Wt,   // [4][FF][DIM]
                 const void* __restrict__ b1,
                 const int* __restrict__ flag,
                 unsigned short* __restrict__ h,          // [4][CAP][FF]
                 const int* __restrict__ dispatch,
                 const int* __restrict__ cnt, int eBase)
{
    constexpr int KT = DIM, NT = FF, NTILES = NT / 128;
    const int el = blockIdx.y, eg = el + eBase;
    const int nt = blockIdx.x % NTILES;
    const int mt = blockIdx.x / NTILES;
    const int m0 = mt * 128, n0 = nt * 128;
    if (m0 >= cnt[eg]) return;               // m-tile fully past expert rows
    const int tid = threadIdx.x, lane = tid & 63, wave = tid >> 6;
    const int wm = wave >> 1, wn = wave & 1;
    const int quad = lane >> 4, l16 = lane & 15;

    __shared__ __align__(16) unsigned short As[128 * 32];
    __shared__ __align__(16) unsigned short Bs[128 * 32];

    const int r0 = tid >> 2, c8 = (tid & 3) * 8;
    int t0 = dispatch[eg * CAP + m0 + r0];
    int t1 = dispatch[eg * CAP + m0 + 64 + r0];
    bool v0 = ((unsigned)t0) < (unsigned)F_TOT;
    bool v1 = ((unsigned)t1) < (unsigned)F_TOT;
    const unsigned short* aS0 = xb + (v0 ? (size_t)t0 * DIM : 0) + c8;
    const unsigned short* aS1 = xb + (v1 ? (size_t)t1 * DIM : 0) + c8;
    const unsigned short* bE  = Wt + (size_t)el * NT * KT;
    const unsigned short* bS0 = bE + (size_t)(n0 + r0) * KT + c8;
    const unsigned short* bS1 = bE + (size_t)(n0 + 64 + r0) * KT + c8;

    f32x4 acc[4][4] = {};

    for (int k0 = 0; k0 < KT; k0 += 32){
        __syncthreads();
        gl_lds16(aS0, &As[tid * 8]);
        gl_lds16(aS1, &As[2048 + tid * 8]);
        gl_lds16(bS0, &Bs[tid * 8]);
        gl_lds16(bS1, &Bs[2048 + tid * 8]);
        aS0 += 32; aS1 += 32; bS0 += 32; bS1 += 32;
        __syncthreads();

        bf16x8 af[4], bfv[4];
        #pragma unroll
        for (int i = 0; i < 4; i++)
            af[i] = *(const bf16x8*)&As[(wm * 64 + i * 16 + l16) * 32 + quad * 8];
        #pragma unroll
        for (int j = 0; j < 4; j++)
            bfv[j] = *(const bf16x8*)&Bs[(wn * 64 + j * 16 + l16) * 32 + quad * 8];
        #pragma unroll
        for (int i = 0; i < 4; i++)
            #pragma unroll
            for (int j = 0; j < 4; j++)
                acc[i][j] = __builtin_amdgcn_mfma_f32_16x16x32_bf16(af[i], bfv[j], acc[i][j], 0, 0, 0);
    }

    const int isb = flag[0];
    const int rB = m0 + wm * 64 + quad * 4;
    const int cB = n0 + wn * 64 + l16;
    float bv[4];
    #pragma unroll
    for (int j = 0; j < 4; j++) bv[j] = ldIn(b1, (size_t)eg * NT + cB + j * 16, isb);
    #pragma unroll
    for (int i = 0; i < 4; i++)
        #pragma unroll
        for (int j = 0; j < 4; j++)
            #pragma unroll
            for (int r = 0; r < 4; r++){
                int row = rB + i * 16 + r;
                float v = acc[i][j][r] + bv[j];
                v = 0.5f * v * (1.0f + erff(v * 0.70710678118654752f));
                h[((size_t)(el * CAP + row)) * FF + cB + j * 16] = f2b(v);
            }
}

// ---------------- ffn1: eo[eg][slot] = h@W2t^T + b2 -------------------------
// grid: x = 8*20 (nt fastest), y = 4 experts
__global__ __launch_bounds__(256, 2)
void ffn1_kernel(const unsigned short* __restrict__ h,    // [4][CAP][FF]
                 const unsigned short* __restrict__ Wt,   // [4][DIM][FF]
                 const void* __restrict__ b2,
                 const int* __restrict__ flag,
                 unsigned short* __restrict__ eo,         // [8][CAP][DIM]
                 const int* __restrict__ cnt, int eBase)
{
    constexpr int KT = FF, NT = DIM, NTILES = NT / 128;
    const int el = blockIdx.y, eg = el + eBase;
    const int nt = blockIdx.x % NTILES;
    const int mt = blockIdx.x / NTILES;
    const int m0 = mt * 128, n0 = nt * 128;
    if (m0 >= cnt[eg]) return;               // m-tile fully past expert rows
    const int tid = threadIdx.x, lane = tid & 63, wave = tid >> 6;
    const int wm = wave >> 1, wn = wave & 1;
    const int quad = lane >> 4, l16 = lane & 15;

    __shared__ __align__(16) unsigned short As[128 * 32];
    __shared__ __align__(16) unsigned short Bs[128 * 32];

    const int r0 = tid >> 2, c8 = (tid & 3) * 8;
    const unsigned short* aS0 = h + ((size_t)(el * CAP + m0 + r0)) * KT + c8;
    const unsigned short* aS1 = h + ((size_t)(el * CAP + m0 + 64 + r0)) * KT + c8;
    const unsigned short* bE  = Wt + (size_t)el * NT * KT;
    const unsigned short* bS0 = bE + (size_t)(n0 + r0) * KT + c8;
    const unsigned short* bS1 = bE + (size_t)(n0 + 64 + r0) * KT + c8;

    f32x4 acc[4][4] = {};

    for (int k0 = 0; k0 < KT; k0 += 32){
        __syncthreads();
        gl_lds16(aS0, &As[tid * 8]);
        gl_lds16(aS1, &As[2048 + tid * 8]);
        gl_lds16(bS0, &Bs[tid * 8]);
        gl_lds16(bS1, &Bs[2048 + tid * 8]);
        aS0 += 32; aS1 += 32; bS0 += 32; bS1 += 32;
        __syncthreads();

        bf16x8 af[4], bfv[4];
        #pragma unroll
        for (int i = 0; i < 4; i++)
            af[i] = *(const bf16x8*)&As[(wm * 64 + i * 16 + l16) * 32 + quad * 8];
        #pragma unroll
        for (int j = 0; j < 4; j++)
            bfv[j] = *(const bf16x8*)&Bs[(wn * 64 + j * 16 + l16) * 32 + quad * 8];
        #pragma unroll
        for (int i = 0; i < 4; i++)
            #pragma unroll
            for (int j = 0; j < 4; j++)
                acc[i][j] = __builtin_amdgcn_mfma_f32_16x16x32_bf16(af[i], bfv[j], acc[i][j], 0, 0, 0);
    }

    const int isb = flag[0];
    const int rB = m0 + wm * 64 + quad * 4;
    const int cB = n0 + wn * 64 + l16;
    float bv[4];
    #pragma unroll
    for (int j = 0; j < 4; j++) bv[j] = ldIn(b2, (size_t)eg * NT + cB + j * 16, isb);
    #pragma unroll
    for (int i = 0; i < 4; i++)
        #pragma unroll
        for (int j = 0; j < 4; j++)
            #pragma unroll
            for (int r = 0; r < 4; r++){
                int row = rB + i * 16 + r;
                eo[((size_t)(eg * CAP + row)) * DIM + cB + j * 16] = f2b(acc[i][j][r] + bv[j]);
            }
}

// ---------------- combine: out[t] = g0*eo[s0] + g1*eo[s1] -------------------
__global__ void combine_kernel(const unsigned short* __restrict__ eo,
                               const int* __restrict__ slotf,
                               const float* __restrict__ gates,
                               const int* __restrict__ flag,
                               void* __restrict__ out)
{
    int t = blockIdx.x;
    int d = threadIdx.x * 4;
    int s0 = slotf[t * 2], s1 = slotf[t * 2 + 1];
    float g0 = gates[t * 2], g1 = gates[t * 2 + 1];
    float a0 = 0.f, a1 = 0.f, a2 = 0.f, a3 = 0.f;
    if (((unsigned)s0) < (unsigned)(NEXP * CAP)){
        ushort4 a = *(const ushort4*)(eo + (size_t)s0 * DIM + d);
        a0 += g0 * b2f(a.x); a1 += g0 * b2f(a.y);
        a2 += g0 * b2f(a.z); a3 += g0 * b2f(a.w);
    }
    if (((unsigned)s1) < (unsigned)(NEXP * CAP)){
        ushort4 a = *(const ushort4*)(eo + (size_t)s1 * DIM + d);
        a0 += g1 * b2f(a.x); a1 += g1 * b2f(a.y);
        a2 += g1 * b2f(a.z); a3 += g1 * b2f(a.w);
    }
    if (flag[0]){
        ushort4 o; o.x = f2b(a0); o.y = f2b(a1); o.z = f2b(a2); o.w = f2b(a3);
        *(ushort4*)((unsigned short*)out + (size_t)t * DIM + d) = o;
    } else {
        float4 o; o.x = a0; o.y = a1; o.z = a2; o.w = a3;
        *(float4*)((float*)out + (size_t)t * DIM + d) = o;
    }
}

// ---------------- launch ----------------------------------------------------
extern "C" void kernel_launch(void* const* d_in, const int* in_sizes, int n_in,
                              void* d_out, int out_size, void* d_ws, size_t ws_size,
                              hipStream_t stream)
{
    const void* x     = d_in[0];
    const void* noise = d_in[1];
    const void* Wg    = d_in[2];
    const void* bg    = d_in[3];
    const void* Wn    = d_in[4];
    const void* bn    = d_in[5];
    const void* W1    = d_in[6];
    const void* b1    = d_in[7];
    const void* W2    = d_in[8];
    const void* b2    = d_in[9];
    char* ws = (char*)d_ws;

    int*   topi    = (int*)  (ws + 524288);       // 65536
    float* gates   = (float*)(ws + 589824);       // 65536
    int*   disp    = (int*)  (ws + 655360);       // 81920
    int*   slotf   = (int*)  (ws + 737280);       // 65536
    int*   flag    = (int*)  (ws + 802816);       // 4
    int*   cnt     = (int*)  (ws + 803072);       // 32
    unsigned short* xb = (unsigned short*)(ws + 1048576);    // 16,777,216
    unsigned short* Wt = (unsigned short*)(ws + 17825792);   // 33,554,432 (4 experts)
    unsigned short* h  = (unsigned short*)(ws + 51380224);   // 83,886,080 (4 experts)
    unsigned short* eo = (unsigned short*)(ws + 135266304);  // 41,943,040 (8 experts)
    // total 177,209,344 B (layout unchanged from round 0)

    gating_kernel<<<512, 256, 0, stream>>>(x, noise, Wg, bg, Wn, bn,
                                           flag, topi, gates, xb);
    scan_kernel<<<8, 1024, 0, stream>>>(topi, disp, slotf, cnt);

    for (int g = 0; g < 2; g++){
        int eB = g * 4;
        transpose_kernel<<<dim3(64, 16, 4), 256, 0, stream>>>(W1, Wt, flag, DIM, FF, eB);
        ffn0_kernel<<<dim3((FF/128) * (CAP/128), 4), 256, 0, stream>>>(
            xb, Wt, b1, flag, h, disp, cnt, eB);
        transpose_kernel<<<dim3(16, 64, 4), 256, 0, stream>>>(W2, Wt, flag, FF, DIM, eB);
        ffn1_kernel<<<dim3((DIM/128) * (CAP/128), 4), 256, 0, stream>>>(
            h, Wt, b2, flag, eo, cnt, eB);
    }
    combine_kernel<<<F_TOT, 256, 0, stream>>>(eo, slotf, gates, flag, d_out);
}

// Round 5
// 848.772 us; speedup vs baseline: 1.0919x; 1.0059x over previous
//
#include <hip/hip_runtime.h>
#include <stdint.h>

typedef __bf16 bf16x8 __attribute__((ext_vector_type(8)));
typedef float  f32x4  __attribute__((ext_vector_type(4)));

#define F_TOT 8192
#define DIM   1024
#define NEXP  8
#define FF    4096
#define CAP   2560

__device__ __forceinline__ float b2f(unsigned short u){
    union { unsigned int u; float f; } c; c.u = ((unsigned int)u) << 16; return c.f;
}
__device__ __forceinline__ unsigned short f2b(float f){
    union { float f; unsigned int u; } c; c.f = f;
    unsigned int r = c.u + 0x7FFFu + ((c.u >> 16) & 1u);
    return (unsigned short)(r >> 16);
}
__device__ __forceinline__ float ldIn(const void* p, size_t i, int isb){
    return isb ? b2f(((const unsigned short*)p)[i]) : ((const float*)p)[i];
}
__device__ __forceinline__ void gl_lds16(const unsigned short* g, unsigned short* l){
    __builtin_amdgcn_global_load_lds(
        (const __attribute__((address_space(1))) unsigned int*)(g),
        (__attribute__((address_space(3))) unsigned int*)(l),
        16, 0, 0);
}

// ---------------- fused: detect + gating + route + convx --------------------
// 512 blocks x 256 threads; block g owns tokens [16g, 16g+16).
__global__ __launch_bounds__(256)
void gating_kernel(const void* __restrict__ x,
                   const void* __restrict__ noise,
                   const void* __restrict__ Wg, const void* __restrict__ bg,
                   const void* __restrict__ Wn, const void* __restrict__ bn,
                   int* __restrict__ flag,
                   int* __restrict__ topi, float* __restrict__ gates,
                   unsigned short* __restrict__ xb)
{
    __shared__ int sflag;
    __shared__ float lg[16][17];     // [token][0..7 logits | 8..15 noise-logits]
    const int g = blockIdx.x, tid = threadIdx.x;
    const unsigned short* xs = (const unsigned short*)x;

    // ---- detect (replicates original 512-sample test per block) ----
    if (tid == 0) sflag = 0;
    __syncthreads();
    {
        int c = 0;
        unsigned short s0 = xs[tid], s1 = xs[tid + 256];
        int e0 = s0 & 0x7F80, e1 = s1 & 0x7F80;
        if (e0 >= 0x3000 && e0 <= 0x4800) c++;
        if (e1 >= 0x3000 && e1 <= 0x4800) c++;
        if (c) atomicAdd(&sflag, c);
    }
    __syncthreads();
    const int isb = (sflag >= 410) ? 1 : 0;
    if (g == 0 && tid == 0) flag[0] = isb;

    // ---- gating dot: 16 tokens x 16 outputs (8 logit + 8 noise-logit) ----
    const int tl = tid >> 4, o = tid & 15, col = o & 7;
    const int t = g * 16 + tl;
    const void* W = (o < 8) ? Wg : Wn;
    float acc = 0.f;
    if (isb){
        const unsigned short* xr = xs + (size_t)t * DIM;
        const unsigned short* w  = (const unsigned short*)W;
        for (int d = 0; d < DIM; d += 8){
            ushort4 a = *(const ushort4*)(xr + d);
            ushort4 b = *(const ushort4*)(xr + d + 4);
            acc = fmaf(b2f(a.x), b2f(w[(d+0)*8+col]), acc);
            acc = fmaf(b2f(a.y), b2f(w[(d+1)*8+col]), acc);
            acc = fmaf(b2f(a.z), b2f(w[(d+2)*8+col]), acc);
            acc = fmaf(b2f(a.w), b2f(w[(d+3)*8+col]), acc);
            acc = fmaf(b2f(b.x), b2f(w[(d+4)*8+col]), acc);
            acc = fmaf(b2f(b.y), b2f(w[(d+5)*8+col]), acc);
            acc = fmaf(b2f(b.z), b2f(w[(d+6)*8+col]), acc);
            acc = fmaf(b2f(b.w), b2f(w[(d+7)*8+col]), acc);
        }
    } else {
        const float* xr = (const float*)x + (size_t)t * DIM;
        const float* w  = (const float*)W;
        for (int d = 0; d < DIM; d += 8){
            float4 a = *(const float4*)(xr + d);
            float4 b = *(const float4*)(xr + d + 4);
            acc = fmaf(a.x, w[(d+0)*8+col], acc);
            acc = fmaf(a.y, w[(d+1)*8+col], acc);
            acc = fmaf(a.z, w[(d+2)*8+col], acc);
            acc = fmaf(a.w, w[(d+3)*8+col], acc);
            acc = fmaf(b.x, w[(d+4)*8+col], acc);
            acc = fmaf(b.y, w[(d+5)*8+col], acc);
            acc = fmaf(b.z, w[(d+6)*8+col], acc);
            acc = fmaf(b.w, w[(d+7)*8+col], acc);
        }
    }
    acc += ldIn((o < 8) ? bg : bn, col, isb);
    lg[tl][o] = acc;
    __syncthreads();

    // ---- route (one thread per token) ----
    if (tid < 16){
        const int tt = g * 16 + tid;
        float ny[8];
        #pragma unroll
        for (int e = 0; e < 8; e++){
            float nl = lg[tid][8 + e];
            float sp = fmaxf(nl, 0.f) + log1pf(expf(-fabsf(nl)));
            ny[e] = lg[tid][e] + ldIn(noise, (size_t)tt * 8 + e, isb) * sp;
        }
        int i0 = 0; float v0 = ny[0];
        #pragma unroll
        for (int e = 1; e < 8; e++) if (ny[e] > v0){ v0 = ny[e]; i0 = e; }
        int i1 = -1; float v1 = -3.4e38f;
        #pragma unroll
        for (int e = 0; e < 8; e++) if (e != i0 && ny[e] > v1){ v1 = ny[e]; i1 = e; }
        float e1 = expf(v1 - v0);
        float den = 1.f + e1;
        topi[tt * 2]      = i0;  topi[tt * 2 + 1] = i1;
        gates[tt * 2]     = 1.f / den;
        gates[tt * 2 + 1] = e1 / den;
    }

    // ---- convx: convert this block's 16 rows (16384 elements) to bf16 ----
    const size_t base = (size_t)g * 16384;
    #pragma unroll
    for (int it = 0; it < 8; it++){
        size_t i = base + (size_t)it * 2048 + tid * 8;
        if (isb){
            ushort4 a = *(const ushort4*)(xs + i);
            ushort4 b = *(const ushort4*)(xs + i + 4);
            *(ushort4*)(xb + i) = a;  *(ushort4*)(xb + i + 4) = b;
        } else {
            float4 a = *(const float4*)((const float*)x + i);
            float4 b = *(const float4*)((const float*)x + i + 4);
            ushort4 lo, hi;
            lo.x = f2b(a.x); lo.y = f2b(a.y); lo.z = f2b(a.z); lo.w = f2b(a.w);
            hi.x = f2b(b.x); hi.y = f2b(b.y); hi.z = f2b(b.z); hi.w = f2b(b.w);
            *(ushort4*)(xb + i) = lo; *(ushort4*)(xb + i + 4) = hi;
        }
    }
}

// ---------------- scan: dispatch[e][pos]=t, slotf[t][k]=e*CAP+pos, cnt[e] ---
__global__ __launch_bounds__(1024)
void scan_kernel(const int* __restrict__ topi,
                 int* __restrict__ dispatch, int* __restrict__ slotf,
                 int* __restrict__ cntbuf)
{
    int e = blockIdx.x;
    int tid = threadIdx.x;
    for (int c = tid; c < CAP; c += 1024) dispatch[e * CAP + c] = F_TOT;
    int base = tid * 8;
    int kk[8]; int cnt = 0;
    #pragma unroll
    for (int j = 0; j < 8; j++){
        int t = base + j;
        int k = (topi[t * 2] == e) ? 0 : ((topi[t * 2 + 1] == e) ? 1 : -1);
        kk[j] = k; if (k >= 0) cnt++;
    }
    __shared__ int s[1024];
    s[tid] = cnt; __syncthreads();
    for (int off = 1; off < 1024; off <<= 1){
        int v = (tid >= off) ? s[tid - off] : 0;
        __syncthreads();
        s[tid] += v;
        __syncthreads();
    }
    if (tid == 1023){ int tot = s[1023]; cntbuf[e] = tot > CAP ? CAP : tot; }
    int pos = s[tid] - cnt;
    #pragma unroll
    for (int j = 0; j < 8; j++){
        if (kk[j] >= 0){
            int t = base + j;
            if (pos < CAP){
                dispatch[e * CAP + pos] = t;
                slotf[t * 2 + kk[j]] = e * CAP + pos;
            } else {
                slotf[t * 2 + kk[j]] = -1;     // dropped (over capacity)
            }
            pos++;
        }
    }
}

// ---------------- transpose (dual-dtype in, bf16 out) -----------------------
__global__ void transpose_kernel(const void* __restrict__ in,
                                 unsigned short* __restrict__ out,
                                 const int* __restrict__ flag,
                                 int R, int C, int eBase)
{
    __shared__ unsigned short tile[64][68];
    const size_t mi = (size_t)(eBase + blockIdx.z) * R * C;
    const size_t mo = (size_t)blockIdx.z * R * C;
    int c0 = blockIdx.x * 64, r0 = blockIdx.y * 64;
    int t = threadIdx.x;
    int rr = t >> 4, cc = (t & 15) * 4;
    int isb = flag[0];
    #pragma unroll
    for (int i = 0; i < 4; i++){
        int r = rr + i * 16;
        size_t idx = mi + (size_t)(r0 + r) * C + c0 + cc;
        if (isb){
            ushort4 v = *(const ushort4*)((const unsigned short*)in + idx);
            *(ushort4*)&tile[r][cc] = v;
        } else {
            float4 v = *(const float4*)((const float*)in + idx);
            ushort4 u; u.x = f2b(v.x); u.y = f2b(v.y); u.z = f2b(v.z); u.w = f2b(v.w);
            *(ushort4*)&tile[r][cc] = u;
        }
    }
    __syncthreads();
    #pragma unroll
    for (int i = 0; i < 4; i++){
        int c = rr + i * 16;
        ushort4 v;
        v.x = tile[cc + 0][c]; v.y = tile[cc + 1][c];
        v.z = tile[cc + 2][c]; v.w = tile[cc + 3][c];
        *(ushort4*)(out + mo + (size_t)(c0 + c) * R + r0 + cc) = v;
    }
}

// ---------------- ffn0: h = gelu(gather(x)@W1t^T + b1) ----------------------
// XCD-clustered: all 32 nt-blocks of one (expert, mt) land on one XCD so the
// shared A-panel is fetched into that XCD's L2 once.
// grid: x = 8 * 3 * 32 = 768 (some idle), y = 4 experts
__global__ __launch_bounds__(256, 2)
void ffn0_kernel(const unsigned short* __restrict__ xb,
                 const unsigned short* __restrict__ Wt,   // [4][FF][DIM]
                 const void* __restrict__ b1,
                 const int* __restrict__ flag,
                 unsigned short* __restrict__ h,          // [4][CAP][FF]
                 const int* __restrict__ dispatch,
                 const int* __restrict__ cnt, int eBase)
{
    constexpr int KT = DIM, NT = FF, NTILES = NT / 128;
    const int el = blockIdx.y, eg = el + eBase;
    const int p = blockIdx.x;
    const int xcd = p & 7, s = p >> 3;
    const int nt = s % NTILES;
    const int mt = xcd + 8 * (s / NTILES);
    if (mt >= CAP / 128) return;
    const int m0 = mt * 128, n0 = nt * 128;
    if (m0 >= cnt[eg]) return;               // m-tile fully past expert rows
    const int tid = threadIdx.x, lane = tid & 63, wave = tid >> 6;
    const int wm = wave >> 1, wn = wave & 1;
    const int quad = lane >> 4, l16 = lane & 15;

    __shared__ __align__(16) unsigned short As[128 * 32];
    __shared__ __align__(16) unsigned short Bs[128 * 32];

    const int r0 = tid >> 2, c8 = (tid & 3) * 8;
    int t0 = dispatch[eg * CAP + m0 + r0];
    int t1 = dispatch[eg * CAP + m0 + 64 + r0];
    bool v0 = ((unsigned)t0) < (unsigned)F_TOT;
    bool v1 = ((unsigned)t1) < (unsigned)F_TOT;
    const unsigned short* aS0 = xb + (v0 ? (size_t)t0 * DIM : 0) + c8;
    const unsigned short* aS1 = xb + (v1 ? (size_t)t1 * DIM : 0) + c8;
    const unsigned short* bE  = Wt + (size_t)el * NT * KT;
    const unsigned short* bS0 = bE + (size_t)(n0 + r0) * KT + c8;
    const unsigned short* bS1 = bE + (size_t)(n0 + 64 + r0) * KT + c8;

    f32x4 acc[4][4] = {};

    for (int k0 = 0; k0 < KT; k0 += 32){
        __syncthreads();
        gl_lds16(aS0, &As[tid * 8]);
        gl_lds16(aS1, &As[2048 + tid * 8]);
        gl_lds16(bS0, &Bs[tid * 8]);
        gl_lds16(bS1, &Bs[2048 + tid * 8]);
        aS0 += 32; aS1 += 32; bS0 += 32; bS1 += 32;
        __syncthreads();

        bf16x8 af[4], bfv[4];
        #pragma unroll
        for (int i = 0; i < 4; i++)
            af[i] = *(const bf16x8*)&As[(wm * 64 + i * 16 + l16) * 32 + quad * 8];
        #pragma unroll
        for (int j = 0; j < 4; j++)
            bfv[j] = *(const bf16x8*)&Bs[(wn * 64 + j * 16 + l16) * 32 + quad * 8];
        #pragma unroll
        for (int i = 0; i < 4; i++)
            #pragma unroll
            for (int j = 0; j < 4; j++)
                acc[i][j] = __builtin_amdgcn_mfma_f32_16x16x32_bf16(af[i], bfv[j], acc[i][j], 0, 0, 0);
    }

    const int isb = flag[0];
    const int rB = m0 + wm * 64 + quad * 4;
    const int cB = n0 + wn * 64 + l16;
    float bv[4];
    #pragma unroll
    for (int j = 0; j < 4; j++) bv[j] = ldIn(b1, (size_t)eg * NT + cB + j * 16, isb);
    #pragma unroll
    for (int i = 0; i < 4; i++)
        #pragma unroll
        for (int j = 0; j < 4; j++)
            #pragma unroll
            for (int r = 0; r < 4; r++){
                int row = rB + i * 16 + r;
                float v = acc[i][j][r] + bv[j];
                v = 0.5f * v * (1.0f + erff(v * 0.70710678118654752f));
                h[((size_t)(el * CAP + row)) * FF + cB + j * 16] = f2b(v);
            }
}

// ---------------- ffn1: eo[eg][slot] = h@W2t^T + b2 -------------------------
// XCD-clustered like ffn0. grid: x = 8 * 3 * 8 = 192, y = 4 experts
__global__ __launch_bounds__(256, 2)
void ffn1_kernel(const unsigned short* __restrict__ h,    // [4][CAP][FF]
                 const unsigned short* __restrict__ Wt,   // [4][DIM][FF]
                 const void* __restrict__ b2,
                 const int* __restrict__ flag,
                 unsigned short* __restrict__ eo,         // [8][CAP][DIM]
                 const int* __restrict__ cnt, int eBase)
{
    constexpr int KT = FF, NT = DIM, NTILES = NT / 128;
    const int el = blockIdx.y, eg = el + eBase;
    const int p = blockIdx.x;
    const int xcd = p & 7, s = p >> 3;
    const int nt = s % NTILES;
    const int mt = xcd + 8 * (s / NTILES);
    if (mt >= CAP / 128) return;
    const int m0 = mt * 128, n0 = nt * 128;
    if (m0 >= cnt[eg]) return;               // m-tile fully past expert rows
    const int tid = threadIdx.x, lane = tid & 63, wave = tid >> 6;
    const int wm = wave >> 1, wn = wave & 1;
    const int quad = lane >> 4, l16 = lane & 15;

    __shared__ __align__(16) unsigned short As[128 * 32];
    __shared__ __align__(16) unsigned short Bs[128 * 32];

    const int r0 = tid >> 2, c8 = (tid & 3) * 8;
    const unsigned short* aS0 = h + ((size_t)(el * CAP + m0 + r0)) * KT + c8;
    const unsigned short* aS1 = h + ((size_t)(el * CAP + m0 + 64 + r0)) * KT + c8;
    const unsigned short* bE  = Wt + (size_t)el * NT * KT;
    const unsigned short* bS0 = bE + (size_t)(n0 + r0) * KT + c8;
    const unsigned short* bS1 = bE + (size_t)(n0 + 64 + r0) * KT + c8;

    f32x4 acc[4][4] = {};

    for (int k0 = 0; k0 < KT; k0 += 32){
        __syncthreads();
        gl_lds16(aS0, &As[tid * 8]);
        gl_lds16(aS1, &As[2048 + tid * 8]);
        gl_lds16(bS0, &Bs[tid * 8]);
        gl_lds16(bS1, &Bs[2048 + tid * 8]);
        aS0 += 32; aS1 += 32; bS0 += 32; bS1 += 32;
        __syncthreads();

        bf16x8 af[4], bfv[4];
        #pragma unroll
        for (int i = 0; i < 4; i++)
            af[i] = *(const bf16x8*)&As[(wm * 64 + i * 16 + l16) * 32 + quad * 8];
        #pragma unroll
        for (int j = 0; j < 4; j++)
            bfv[j] = *(const bf16x8*)&Bs[(wn * 64 + j * 16 + l16) * 32 + quad * 8];
        #pragma unroll
        for (int i = 0; i < 4; i++)
            #pragma unroll
            for (int j = 0; j < 4; j++)
                acc[i][j] = __builtin_amdgcn_mfma_f32_16x16x32_bf16(af[i], bfv[j], acc[i][j], 0, 0, 0);
    }

    const int isb = flag[0];
    const int rB = m0 + wm * 64 + quad * 4;
    const int cB = n0 + wn * 64 + l16;
    float bv[4];
    #pragma unroll
    for (int j = 0; j < 4; j++) bv[j] = ldIn(b2, (size_t)eg * NT + cB + j * 16, isb);
    #pragma unroll
    for (int i = 0; i < 4; i++)
        #pragma unroll
        for (int j = 0; j < 4; j++)
            #pragma unroll
            for (int r = 0; r < 4; r++){
                int row = rB + i * 16 + r;
                eo[((size_t)(eg * CAP + row)) * DIM + cB + j * 16] = f2b(acc[i][j][r] + bv[j]);
            }
}

// ---------------- combine: out[t] = g0*eo[s0] + g1*eo[s1] -------------------
__global__ void combine_kernel(const unsigned short* __restrict__ eo,
                               const int* __restrict__ slotf,
                               const float* __restrict__ gates,
                               const int* __restrict__ flag,
                               void* __restrict__ out)
{
    int t = blockIdx.x;
    int d = threadIdx.x * 4;
    int s0 = slotf[t * 2], s1 = slotf[t * 2 + 1];
    float g0 = gates[t * 2], g1 = gates[t * 2 + 1];
    float a0 = 0.f, a1 = 0.f, a2 = 0.f, a3 = 0.f;
    if (((unsigned)s0) < (unsigned)(NEXP * CAP)){
        ushort4 a = *(const ushort4*)(eo + (size_t)s0 * DIM + d);
        a0 += g0 * b2f(a.x); a1 += g0 * b2f(a.y);
        a2 += g0 * b2f(a.z); a3 += g0 * b2f(a.w);
    }
    if (((unsigned)s1) < (unsigned)(NEXP * CAP)){
        ushort4 a = *(const ushort4*)(eo + (size_t)s1 * DIM + d);
        a0 += g1 * b2f(a.x); a1 += g1 * b2f(a.y);
        a2 += g1 * b2f(a.z); a3 += g1 * b2f(a.w);
    }
    if (flag[0]){
        ushort4 o; o.x = f2b(a0); o.y = f2b(a1); o.z = f2b(a2); o.w = f2b(a3);
        *(ushort4*)((unsigned short*)out + (size_t)t * DIM + d) = o;
    } else {
        float4 o; o.x = a0; o.y = a1; o.z = a2; o.w = a3;
        *(float4*)((float*)out + (size_t)t * DIM + d) = o;
    }
}

// ---------------- launch ----------------------------------------------------
extern "C" void kernel_launch(void* const* d_in, const int* in_sizes, int n_in,
                              void* d_out, int out_size, void* d_ws, size_t ws_size,
                              hipStream_t stream)
{
    const void* x     = d_in[0];
    const void* noise = d_in[1];
    const void* Wg    = d_in[2];
    const void* bg    = d_in[3];
    const void* Wn    = d_in[4];
    const void* bn    = d_in[5];
    const void* W1    = d_in[6];
    const void* b1    = d_in[7];
    const void* W2    = d_in[8];
    const void* b2    = d_in[9];
    char* ws = (char*)d_ws;

    int*   topi    = (int*)  (ws + 524288);       // 65536
    float* gates   = (float*)(ws + 589824);       // 65536
    int*   disp    = (int*)  (ws + 655360);       // 81920
    int*   slotf   = (int*)  (ws + 737280);       // 65536
    int*   flag    = (int*)  (ws + 802816);       // 4
    int*   cnt     = (int*)  (ws + 803072);       // 32
    unsigned short* xb = (unsigned short*)(ws + 1048576);    // 16,777,216
    unsigned short* Wt = (unsigned short*)(ws + 17825792);   // 33,554,432 (4 experts)
    unsigned short* h  = (unsigned short*)(ws + 51380224);   // 83,886,080 (4 experts)
    unsigned short* eo = (unsigned short*)(ws + 135266304);  // 41,943,040 (8 experts)
    // total 177,209,344 B (layout unchanged from round 0)

    gating_kernel<<<512, 256, 0, stream>>>(x, noise, Wg, bg, Wn, bn,
                                           flag, topi, gates, xb);
    scan_kernel<<<8, 1024, 0, stream>>>(topi, disp, slotf, cnt);

    for (int g = 0; g < 2; g++){
        int eB = g * 4;
        transpose_kernel<<<dim3(64, 16, 4), 256, 0, stream>>>(W1, Wt, flag, DIM, FF, eB);
        ffn0_kernel<<<dim3(8 * 3 * (FF/128), 4), 256, 0, stream>>>(
            xb, Wt, b1, flag, h, disp, cnt, eB);
        transpose_kernel<<<dim3(16, 64, 4), 256, 0, stream>>>(W2, Wt, flag, FF, DIM, eB);
        ffn1_kernel<<<dim3(8 * 3 * (DIM/128), 4), 256, 0, stream>>>(
            h, Wt, b2, flag, eo, cnt, eB);
    }
    combine_kernel<<<F_TOT, 256, 0, stream>>>(eo, slotf, gates, flag, d_out);
}

// Round 6
// 818.292 us; speedup vs baseline: 1.1326x; 1.0372x over previous
//
#include <hip/hip_runtime.h>
#include <stdint.h>

typedef __bf16 bf16x8 __attribute__((ext_vector_type(8)));
typedef float  f32x4  __attribute__((ext_vector_type(4)));

#define F_TOT 8192
#define DIM   1024
#define NEXP  8
#define FF    4096
#define CAP   2560

__device__ __forceinline__ float b2f(unsigned short u){
    union { unsigned int u; float f; } c; c.u = ((unsigned int)u) << 16; return c.f;
}
__device__ __forceinline__ unsigned short f2b(float f){
    union { float f; unsigned int u; } c; c.f = f;
    unsigned int r = c.u + 0x7FFFu + ((c.u >> 16) & 1u);
    return (unsigned short)(r >> 16);
}
__device__ __forceinline__ float ldIn(const void* p, size_t i, int isb){
    return isb ? b2f(((const unsigned short*)p)[i]) : ((const float*)p)[i];
}
__device__ __forceinline__ void gl_lds16(const unsigned short* g, unsigned short* l){
    __builtin_amdgcn_global_load_lds(
        (const __attribute__((address_space(1))) unsigned int*)(g),
        (__attribute__((address_space(3))) unsigned int*)(l),
        16, 0, 0);
}

// ---------------- fused: detect + gating + route + convx --------------------
// 512 blocks x 256 threads; block g owns tokens [16g, 16g+16).
__global__ __launch_bounds__(256)
void gating_kernel(const void* __restrict__ x,
                   const void* __restrict__ noise,
                   const void* __restrict__ Wg, const void* __restrict__ bg,
                   const void* __restrict__ Wn, const void* __restrict__ bn,
                   int* __restrict__ flag,
                   int* __restrict__ topi, float* __restrict__ gates,
                   unsigned short* __restrict__ xb)
{
    __shared__ int sflag;
    __shared__ float lg[16][17];     // [token][0..7 logits | 8..15 noise-logits]
    const int g = blockIdx.x, tid = threadIdx.x;
    const unsigned short* xs = (const unsigned short*)x;

    // ---- detect (replicates original 512-sample test per block) ----
    if (tid == 0) sflag = 0;
    __syncthreads();
    {
        int c = 0;
        unsigned short s0 = xs[tid], s1 = xs[tid + 256];
        int e0 = s0 & 0x7F80, e1 = s1 & 0x7F80;
        if (e0 >= 0x3000 && e0 <= 0x4800) c++;
        if (e1 >= 0x3000 && e1 <= 0x4800) c++;
        if (c) atomicAdd(&sflag, c);
    }
    __syncthreads();
    const int isb = (sflag >= 410) ? 1 : 0;
    if (g == 0 && tid == 0) flag[0] = isb;

    // ---- gating dot: 16 tokens x 16 outputs (8 logit + 8 noise-logit) ----
    const int tl = tid >> 4, o = tid & 15, col = o & 7;
    const int t = g * 16 + tl;
    const void* W = (o < 8) ? Wg : Wn;
    float acc = 0.f;
    if (isb){
        const unsigned short* xr = xs + (size_t)t * DIM;
        const unsigned short* w  = (const unsigned short*)W;
        for (int d = 0; d < DIM; d += 8){
            ushort4 a = *(const ushort4*)(xr + d);
            ushort4 b = *(const ushort4*)(xr + d + 4);
            acc = fmaf(b2f(a.x), b2f(w[(d+0)*8+col]), acc);
            acc = fmaf(b2f(a.y), b2f(w[(d+1)*8+col]), acc);
            acc = fmaf(b2f(a.z), b2f(w[(d+2)*8+col]), acc);
            acc = fmaf(b2f(a.w), b2f(w[(d+3)*8+col]), acc);
            acc = fmaf(b2f(b.x), b2f(w[(d+4)*8+col]), acc);
            acc = fmaf(b2f(b.y), b2f(w[(d+5)*8+col]), acc);
            acc = fmaf(b2f(b.z), b2f(w[(d+6)*8+col]), acc);
            acc = fmaf(b2f(b.w), b2f(w[(d+7)*8+col]), acc);
        }
    } else {
        const float* xr = (const float*)x + (size_t)t * DIM;
        const float* w  = (const float*)W;
        for (int d = 0; d < DIM; d += 8){
            float4 a = *(const float4*)(xr + d);
            float4 b = *(const float4*)(xr + d + 4);
            acc = fmaf(a.x, w[(d+0)*8+col], acc);
            acc = fmaf(a.y, w[(d+1)*8+col], acc);
            acc = fmaf(a.z, w[(d+2)*8+col], acc);
            acc = fmaf(a.w, w[(d+3)*8+col], acc);
            acc = fmaf(b.x, w[(d+4)*8+col], acc);
            acc = fmaf(b.y, w[(d+5)*8+col], acc);
            acc = fmaf(b.z, w[(d+6)*8+col], acc);
            acc = fmaf(b.w, w[(d+7)*8+col], acc);
        }
    }
    acc += ldIn((o < 8) ? bg : bn, col, isb);
    lg[tl][o] = acc;
    __syncthreads();

    // ---- route (one thread per token) ----
    if (tid < 16){
        const int tt = g * 16 + tid;
        float ny[8];
        #pragma unroll
        for (int e = 0; e < 8; e++){
            float nl = lg[tid][8 + e];
            float sp = fmaxf(nl, 0.f) + log1pf(expf(-fabsf(nl)));
            ny[e] = lg[tid][e] + ldIn(noise, (size_t)tt * 8 + e, isb) * sp;
        }
        int i0 = 0; float v0 = ny[0];
        #pragma unroll
        for (int e = 1; e < 8; e++) if (ny[e] > v0){ v0 = ny[e]; i0 = e; }
        int i1 = -1; float v1 = -3.4e38f;
        #pragma unroll
        for (int e = 0; e < 8; e++) if (e != i0 && ny[e] > v1){ v1 = ny[e]; i1 = e; }
        float e1 = expf(v1 - v0);
        float den = 1.f + e1;
        topi[tt * 2]      = i0;  topi[tt * 2 + 1] = i1;
        gates[tt * 2]     = 1.f / den;
        gates[tt * 2 + 1] = e1 / den;
    }

    // ---- convx: convert this block's 16 rows (16384 elements) to bf16 ----
    const size_t base = (size_t)g * 16384;
    #pragma unroll
    for (int it = 0; it < 8; it++){
        size_t i = base + (size_t)it * 2048 + tid * 8;
        if (isb){
            ushort4 a = *(const ushort4*)(xs + i);
            ushort4 b = *(const ushort4*)(xs + i + 4);
            *(ushort4*)(xb + i) = a;  *(ushort4*)(xb + i + 4) = b;
        } else {
            float4 a = *(const float4*)((const float*)x + i);
            float4 b = *(const float4*)((const float*)x + i + 4);
            ushort4 lo, hi;
            lo.x = f2b(a.x); lo.y = f2b(a.y); lo.z = f2b(a.z); lo.w = f2b(a.w);
            hi.x = f2b(b.x); hi.y = f2b(b.y); hi.z = f2b(b.z); hi.w = f2b(b.w);
            *(ushort4*)(xb + i) = lo; *(ushort4*)(xb + i + 4) = hi;
        }
    }
}

// ---------------- scan: dispatch[e][pos]=t, slotf[t][k]=e*CAP+pos, cnt[e] ---
__global__ __launch_bounds__(1024)
void scan_kernel(const int* __restrict__ topi,
                 int* __restrict__ dispatch, int* __restrict__ slotf,
                 int* __restrict__ cntbuf)
{
    int e = blockIdx.x;
    int tid = threadIdx.x;
    for (int c = tid; c < CAP; c += 1024) dispatch[e * CAP + c] = F_TOT;
    int base = tid * 8;
    int kk[8]; int cnt = 0;
    #pragma unroll
    for (int j = 0; j < 8; j++){
        int t = base + j;
        int k = (topi[t * 2] == e) ? 0 : ((topi[t * 2 + 1] == e) ? 1 : -1);
        kk[j] = k; if (k >= 0) cnt++;
    }
    __shared__ int s[1024];
    s[tid] = cnt; __syncthreads();
    for (int off = 1; off < 1024; off <<= 1){
        int v = (tid >= off) ? s[tid - off] : 0;
        __syncthreads();
        s[tid] += v;
        __syncthreads();
    }
    if (tid == 1023){ int tot = s[1023]; cntbuf[e] = tot > CAP ? CAP : tot; }
    int pos = s[tid] - cnt;
    #pragma unroll
    for (int j = 0; j < 8; j++){
        if (kk[j] >= 0){
            int t = base + j;
            if (pos < CAP){
                dispatch[e * CAP + pos] = t;
                slotf[t * 2 + kk[j]] = e * CAP + pos;
            } else {
                slotf[t * 2 + kk[j]] = -1;     // dropped (over capacity)
            }
            pos++;
        }
    }
}

// ---------------- transpose (dual-dtype in, bf16 out) -----------------------
__global__ void transpose_kernel(const void* __restrict__ in,
                                 unsigned short* __restrict__ out,
                                 const int* __restrict__ flag,
                                 int R, int C, int eBase)
{
    __shared__ unsigned short tile[64][68];
    const size_t mi = (size_t)(eBase + blockIdx.z) * R * C;
    const size_t mo = (size_t)blockIdx.z * R * C;
    int c0 = blockIdx.x * 64, r0 = blockIdx.y * 64;
    int t = threadIdx.x;
    int rr = t >> 4, cc = (t & 15) * 4;
    int isb = flag[0];
    #pragma unroll
    for (int i = 0; i < 4; i++){
        int r = rr + i * 16;
        size_t idx = mi + (size_t)(r0 + r) * C + c0 + cc;
        if (isb){
            ushort4 v = *(const ushort4*)((const unsigned short*)in + idx);
            *(ushort4*)&tile[r][cc] = v;
        } else {
            float4 v = *(const float4*)((const float*)in + idx);
            ushort4 u; u.x = f2b(v.x); u.y = f2b(v.y); u.z = f2b(v.z); u.w = f2b(v.w);
            *(ushort4*)&tile[r][cc] = u;
        }
    }
    __syncthreads();
    #pragma unroll
    for (int i = 0; i < 4; i++){
        int c = rr + i * 16;
        ushort4 v;
        v.x = tile[cc + 0][c]; v.y = tile[cc + 1][c];
        v.z = tile[cc + 2][c]; v.w = tile[cc + 3][c];
        *(ushort4*)(out + mo + (size_t)(c0 + c) * R + r0 + cc) = v;
    }
}

// ---------------- ffn0: h = gelu(gather(x)@W1t^T + b1) ----------------------
// Linear grid (nt fastest) — measured best (round 4: FETCH 88MB).
// A (=xb, 16.8MB) is L3-resident; XCD clustering only thrashes B's L2 (round 5).
// grid: x = 32*20, y = 4 experts
__global__ __launch_bounds__(256, 2)
void ffn0_kernel(const unsigned short* __restrict__ xb,
                 const unsigned short* __restrict__ Wt,   // [4][FF][DIM]
                 const void* __restrict__ b1,
                 const int* __restrict__ flag,
                 unsigned short* __restrict__ h,          // [4][CAP][FF]
                 const int* __restrict__ dispatch,
                 const int* __restrict__ cnt, int eBase)
{
    constexpr int KT = DIM, NT = FF, NTILES = NT / 128;
    const int el = blockIdx.y, eg = el + eBase;
    const int nt = blockIdx.x % NTILES;
    const int mt = blockIdx.x / NTILES;
    const int m0 = mt * 128, n0 = nt * 128;
    if (m0 >= cnt[eg]) return;               // m-tile fully past expert rows
    const int tid = threadIdx.x, lane = tid & 63, wave = tid >> 6;
    const int wm = wave >> 1, wn = wave & 1;
    const int quad = lane >> 4, l16 = lane & 15;

    __shared__ __align__(16) unsigned short As[128 * 32];
    __shared__ __align__(16) unsigned short Bs[128 * 32];

    const int r0 = tid >> 2, c8 = (tid & 3) * 8;
    int t0 = dispatch[eg * CAP + m0 + r0];
    int t1 = dispatch[eg * CAP + m0 + 64 + r0];
    bool v0 = ((unsigned)t0) < (unsigned)F_TOT;
    bool v1 = ((unsigned)t1) < (unsigned)F_TOT;
    const unsigned short* aS0 = xb + (v0 ? (size_t)t0 * DIM : 0) + c8;
    const unsigned short* aS1 = xb + (v1 ? (size_t)t1 * DIM : 0) + c8;
    const unsigned short* bE  = Wt + (size_t)el * NT * KT;
    const unsigned short* bS0 = bE + (size_t)(n0 + r0) * KT + c8;
    const unsigned short* bS1 = bE + (size_t)(n0 + 64 + r0) * KT + c8;

    f32x4 acc[4][4] = {};

    for (int k0 = 0; k0 < KT; k0 += 32){
        __syncthreads();
        gl_lds16(aS0, &As[tid * 8]);
        gl_lds16(aS1, &As[2048 + tid * 8]);
        gl_lds16(bS0, &Bs[tid * 8]);
        gl_lds16(bS1, &Bs[2048 + tid * 8]);
        aS0 += 32; aS1 += 32; bS0 += 32; bS1 += 32;
        __syncthreads();

        bf16x8 af[4], bfv[4];
        #pragma unroll
        for (int i = 0; i < 4; i++)
            af[i] = *(const bf16x8*)&As[(wm * 64 + i * 16 + l16) * 32 + quad * 8];
        #pragma unroll
        for (int j = 0; j < 4; j++)
            bfv[j] = *(const bf16x8*)&Bs[(wn * 64 + j * 16 + l16) * 32 + quad * 8];
        #pragma unroll
        for (int i = 0; i < 4; i++)
            #pragma unroll
            for (int j = 0; j < 4; j++)
                acc[i][j] = __builtin_amdgcn_mfma_f32_16x16x32_bf16(af[i], bfv[j], acc[i][j], 0, 0, 0);
    }

    const int isb = flag[0];
    const int rB = m0 + wm * 64 + quad * 4;
    const int cB = n0 + wn * 64 + l16;
    float bv[4];
    #pragma unroll
    for (int j = 0; j < 4; j++) bv[j] = ldIn(b1, (size_t)eg * NT + cB + j * 16, isb);
    #pragma unroll
    for (int i = 0; i < 4; i++)
        #pragma unroll
        for (int j = 0; j < 4; j++)
            #pragma unroll
            for (int r = 0; r < 4; r++){
                int row = rB + i * 16 + r;
                float v = acc[i][j][r] + bv[j];
                v = 0.5f * v * (1.0f + erff(v * 0.70710678118654752f));
                h[((size_t)(el * CAP + row)) * FF + cB + j * 16] = f2b(v);
            }
}

// ---------------- ffn1: eo[eg][slot] = h@W2t^T + b2 -------------------------
// XCD-clustered (measured good in round 5: A=h is 84MB, not L3-resident;
// clustering the 8 A-panel sharers on one XCD de-duplicates HBM fetches).
// grid: x = 8 * 3 * 8 = 192, y = 4 experts
__global__ __launch_bounds__(256, 2)
void ffn1_kernel(const unsigned short* __restrict__ h,    // [4][CAP][FF]
                 const unsigned short* __restrict__ Wt,   // [4][DIM][FF]
                 const void* __restrict__ b2,
                 const int* __restrict__ flag,
                 unsigned short* __restrict__ eo,         // [8][CAP][DIM]
                 const int* __restrict__ cnt, int eBase)
{
    constexpr int KT = FF, NT = DIM, NTILES = NT / 128;
    const int el = blockIdx.y, eg = el + eBase;
    const int p = blockIdx.x;
    const int xcd = p & 7, s = p >> 3;
    const int nt = s % NTILES;
    const int mt = xcd + 8 * (s / NTILES);
    if (mt >= CAP / 128) return;
    const int m0 = mt * 128, n0 = nt * 128;
    if (m0 >= cnt[eg]) return;               // m-tile fully past expert rows
    const int tid = threadIdx.x, lane = tid & 63, wave = tid >> 6;
    const int wm = wave >> 1, wn = wave & 1;
    const int quad = lane >> 4, l16 = lane & 15;

    __shared__ __align__(16) unsigned short As[128 * 32];
    __shared__ __align__(16) unsigned short Bs[128 * 32];

    const int r0 = tid >> 2, c8 = (tid & 3) * 8;
    const unsigned short* aS0 = h + ((size_t)(el * CAP + m0 + r0)) * KT + c8;
    const unsigned short* aS1 = h + ((size_t)(el * CAP + m0 + 64 + r0)) * KT + c8;
    const unsigned short* bE  = Wt + (size_t)el * NT * KT;
    const unsigned short* bS0 = bE + (size_t)(n0 + r0) * KT + c8;
    const unsigned short* bS1 = bE + (size_t)(n0 + 64 + r0) * KT + c8;

    f32x4 acc[4][4] = {};

    for (int k0 = 0; k0 < KT; k0 += 32){
        __syncthreads();
        gl_lds16(aS0, &As[tid * 8]);
        gl_lds16(aS1, &As[2048 + tid * 8]);
        gl_lds16(bS0, &Bs[tid * 8]);
        gl_lds16(bS1, &Bs[2048 + tid * 8]);
        aS0 += 32; aS1 += 32; bS0 += 32; bS1 += 32;
        __syncthreads();

        bf16x8 af[4], bfv[4];
        #pragma unroll
        for (int i = 0; i < 4; i++)
            af[i] = *(const bf16x8*)&As[(wm * 64 + i * 16 + l16) * 32 + quad * 8];
        #pragma unroll
        for (int j = 0; j < 4; j++)
            bfv[j] = *(const bf16x8*)&Bs[(wn * 64 + j * 16 + l16) * 32 + quad * 8];
        #pragma unroll
        for (int i = 0; i < 4; i++)
            #pragma unroll
            for (int j = 0; j < 4; j++)
                acc[i][j] = __builtin_amdgcn_mfma_f32_16x16x32_bf16(af[i], bfv[j], acc[i][j], 0, 0, 0);
    }

    const int isb = flag[0];
    const int rB = m0 + wm * 64 + quad * 4;
    const int cB = n0 + wn * 64 + l16;
    float bv[4];
    #pragma unroll
    for (int j = 0; j < 4; j++) bv[j] = ldIn(b2, (size_t)eg * NT + cB + j * 16, isb);
    #pragma unroll
    for (int i = 0; i < 4; i++)
        #pragma unroll
        for (int j = 0; j < 4; j++)
            #pragma unroll
            for (int r = 0; r < 4; r++){
                int row = rB + i * 16 + r;
                eo[((size_t)(eg * CAP + row)) * DIM + cB + j * 16] = f2b(acc[i][j][r] + bv[j]);
            }
}

// ---------------- combine: out[t] = g0*eo[s0] + g1*eo[s1] -------------------
__global__ void combine_kernel(const unsigned short* __restrict__ eo,
                               const int* __restrict__ slotf,
                               const float* __restrict__ gates,
                               const int* __restrict__ flag,
                               void* __restrict__ out)
{
    int t = blockIdx.x;
    int d = threadIdx.x * 4;
    int s0 = slotf[t * 2], s1 = slotf[t * 2 + 1];
    float g0 = gates[t * 2], g1 = gates[t * 2 + 1];
    float a0 = 0.f, a1 = 0.f, a2 = 0.f, a3 = 0.f;
    if (((unsigned)s0) < (unsigned)(NEXP * CAP)){
        ushort4 a = *(const ushort4*)(eo + (size_t)s0 * DIM + d);
        a0 += g0 * b2f(a.x); a1 += g0 * b2f(a.y);
        a2 += g0 * b2f(a.z); a3 += g0 * b2f(a.w);
    }
    if (((unsigned)s1) < (unsigned)(NEXP * CAP)){
        ushort4 a = *(const ushort4*)(eo + (size_t)s1 * DIM + d);
        a0 += g1 * b2f(a.x); a1 += g1 * b2f(a.y);
        a2 += g1 * b2f(a.z); a3 += g1 * b2f(a.w);
    }
    if (flag[0]){
        ushort4 o; o.x = f2b(a0); o.y = f2b(a1); o.z = f2b(a2); o.w = f2b(a3);
        *(ushort4*)((unsigned short*)out + (size_t)t * DIM + d) = o;
    } else {
        float4 o; o.x = a0; o.y = a1; o.z = a2; o.w = a3;
        *(float4*)((float*)out + (size_t)t * DIM + d) = o;
    }
}

// ---------------- launch ----------------------------------------------------
extern "C" void kernel_launch(void* const* d_in, const int* in_sizes, int n_in,
                              void* d_out, int out_size, void* d_ws, size_t ws_size,
                              hipStream_t stream)
{
    const void* x     = d_in[0];
    const void* noise = d_in[1];
    const void* Wg    = d_in[2];
    const void* bg    = d_in[3];
    const void* Wn    = d_in[4];
    const void* bn    = d_in[5];
    const void* W1    = d_in[6];
    const void* b1    = d_in[7];
    const void* W2    = d_in[8];
    const void* b2    = d_in[9];
    char* ws = (char*)d_ws;

    int*   topi    = (int*)  (ws + 524288);       // 65536
    float* gates   = (float*)(ws + 589824);       // 65536
    int*   disp    = (int*)  (ws + 655360);       // 81920
    int*   slotf   = (int*)  (ws + 737280);       // 65536
    int*   flag    = (int*)  (ws + 802816);       // 4
    int*   cnt     = (int*)  (ws + 803072);       // 32
    unsigned short* xb = (unsigned short*)(ws + 1048576);    // 16,777,216
    unsigned short* Wt = (unsigned short*)(ws + 17825792);   // 33,554,432 (4 experts)
    unsigned short* h  = (unsigned short*)(ws + 51380224);   // 83,886,080 (4 experts)
    unsigned short* eo = (unsigned short*)(ws + 135266304);  // 41,943,040 (8 experts)
    // total 177,209,344 B (layout unchanged from round 0)

    gating_kernel<<<512, 256, 0, stream>>>(x, noise, Wg, bg, Wn, bn,
                                           flag, topi, gates, xb);
    scan_kernel<<<8, 1024, 0, stream>>>(topi, disp, slotf, cnt);

    for (int g = 0; g < 2; g++){
        int eB = g * 4;
        transpose_kernel<<<dim3(64, 16, 4), 256, 0, stream>>>(W1, Wt, flag, DIM, FF, eB);
        ffn0_kernel<<<dim3((FF/128) * (CAP/128), 4), 256, 0, stream>>>(
            xb, Wt, b1, flag, h, disp, cnt, eB);
        transpose_kernel<<<dim3(16, 64, 4), 256, 0, stream>>>(W2, Wt, flag, FF, DIM, eB);
        ffn1_kernel<<<dim3(8 * 3 * (DIM/128), 4), 256, 0, stream>>>(
            h, Wt, b2, flag, eo, cnt, eB);
    }
    combine_kernel<<<F_TOT, 256, 0, stream>>>(eo, slotf, gates, flag, d_out);
}